// Round 14
// baseline (682.717 us; speedup 1.0000x reference)
//
#include <hip/hip_runtime.h>

typedef __bf16 bf16x8 __attribute__((ext_vector_type(8)));
typedef short short8_t __attribute__((ext_vector_type(8)));
typedef float f32x4 __attribute__((ext_vector_type(4)));
typedef float f32x16 __attribute__((ext_vector_type(16)));
typedef int int2v __attribute__((ext_vector_type(2)));
typedef unsigned short us4_t __attribute__((ext_vector_type(4)));

#define SCALE 0.08838834764831845f  // 1/sqrt(128)
#define CEXP 0.1275179f             // SCALE * log2(e)

#define VMCNT(n) asm volatile("s_waitcnt vmcnt(" #n ")" ::: "memory")

__device__ __forceinline__ float b2f(unsigned short u) {
  union { unsigned int i; float f; } v; v.i = ((unsigned int)u) << 16; return v.f;
}
__device__ __forceinline__ unsigned short f2b(float f) {
  union { float f; unsigned int i; } v; v.f = f;
  unsigned int r = v.i + 0x7fffu + ((v.i >> 16) & 1u);
  return (unsigned short)(r >> 16);
}

__device__ __forceinline__ f32x16 mfma32(short8_t a, short8_t b, f32x16 c) {
  return __builtin_amdgcn_mfma_f32_32x32x16_bf16(
      __builtin_bit_cast(bf16x8, a), __builtin_bit_cast(bf16x8, b), c, 0, 0, 0);
}

typedef __attribute__((address_space(1))) const void gas_t;
typedef __attribute__((address_space(3))) void las_t;
__device__ __forceinline__ void gload16(const void* g, void* l) {
  __builtin_amdgcn_global_load_lds((gas_t*)g, (las_t*)l, 16, 0, 0);
}

// ---------------- fp32 -> bf16 convert ----------------
__global__ void cvt_kernel(const float* __restrict__ src, unsigned short* __restrict__ dst, int n4) {
  for (int i = blockIdx.x * blockDim.x + threadIdx.x; i < n4; i += gridDim.x * blockDim.x) {
    f32x4 v = *(const f32x4*)(src + (size_t)i * 4);
    us4_t o;
    o[0] = f2b(v[0]); o[1] = f2b(v[1]); o[2] = f2b(v[2]); o[3] = f2b(v[3]);
    *(us4_t*)(dst + (size_t)i * 4) = o;
  }
}

// ============ 256x256 counted-vmcnt pipelined GEMM core (C = A * Bt^T) ============
// BK=32, 4 LDS slots (stage lead 3), 8 waves (2M x 4N), ONE phase per K-tile,
// mfma_f32_32x32x16_bf16 (17% lower MFMA-issue floor than 16x16x32 pair).
// Per wave: output 128x64 = 4(mi) x 2(nj) fragments of 32x32, f32x16 each.
// Fragment maps (HW-verified in attn kernel): A/B lane l -> row/col (l&31),
// k = kk*16 + (l>>5)*8 .. +8;  C/D elem r -> A-row (r&3)+8*(r>>2)+4*(l>>5),
// B-col (l&31).
// LDS layout (shorts): A-slots [0,32768): slot s at s*8192; B-slots [32768,65536).
// Element (row r, k-block j of 8) at byte r*64 + (j ^ ((r>>1)&3))*16 (both sides).
// MODE: 0 = f32 out, 1 = bf16 out, 2 = bf16 transposed-V out
template <int MODE>
__device__ __forceinline__ void gemm256_core(
    unsigned short* __restrict__ lds,
    const unsigned short* __restrict__ A, const unsigned short* __restrict__ Bt,
    void* __restrict__ Cout, int m0, int n0, int K, int ldc) {
  const int tid = threadIdx.x;
  const int wid = tid >> 6, lane = tid & 63;
  const int l31 = lane & 31, lh = lane >> 5;
  const int wm = wid >> 2, wn = wid & 3;
  const int NT = K >> 5;

  // ---- staging geometry (identical to R12): per gload round, wave covers 16 rows
  const int sr0 = wid * 16 + (lane >> 2);
  const int sr1 = 128 + sr0;
  const int sj0 = ((lane & 3) ^ ((sr0 >> 1) & 3)) * 8;   // inverse-swizzled source block
  const int sj1 = ((lane & 3) ^ ((sr1 >> 1) & 3)) * 8;
  const unsigned short* gA0 = A + (size_t)(m0 + sr0) * K + sj0;
  const unsigned short* gA1 = A + (size_t)(m0 + sr1) * K + sj1;
  const unsigned short* gB0 = Bt + (size_t)(n0 + sr0) * K + sj0;
  const unsigned short* gB1 = Bt + (size_t)(n0 + sr1) * K + sj1;
  unsigned short* dA = lds + wid * 512;
  unsigned short* dB = lds + 32768 + wid * 512;

  // ---- ds_read fragment addressing (bytes) for 32x32 fragments
  // row = base + l31; swizzle index ((row>>1)&3) == ((l31>>1)&3) since
  // mi*32 / nj*32 / wm*128 / wn*64 are all == 0 mod 4 after >>1.
  const int sw = (l31 >> 1) & 3;
  const unsigned char* ldsb = (const unsigned char*)lds;
  const int aoff = (wm * 128 + l31) * 64;           // + mi*2048 + jterm + slot*16384
  const int boff = 65536 + (wn * 64 + l31) * 64;    // + nj*2048 + jterm + slot*16384
  // jterm for (kk, lh): ((kk*2 + lh) ^ sw) << 4
  const int jt0 = ((0 + lh) ^ sw) << 4;             // kk=0
  const int jt1 = ((2 + lh) ^ sw) << 4;             // kk=1

  f32x16 acc[4][2] = {};

#define STAGE_A(t_) { int s_ = (t_) & 3; int k0_ = (t_) << 5; \
    gload16(gA0 + k0_, dA + s_ * 8192); \
    gload16(gA1 + k0_, dA + s_ * 8192 + 4096); }
#define STAGE_B(t_) { int s_ = (t_) & 3; int k0_ = (t_) << 5; \
    gload16(gB0 + k0_, dB + s_ * 8192); \
    gload16(gB1 + k0_, dB + s_ * 8192 + 4096); }

  // prologue: stage tiles 0,1,2; confirm tile 0 (8 newer loads stay in flight)
  STAGE_A(0); STAGE_B(0);
  STAGE_A(1); STAGE_B(1);
  STAGE_A(2); STAGE_B(2);
  VMCNT(8);
  __builtin_amdgcn_s_barrier();

  for (int t = 0; t < NT; ++t) {
    const int sb = (t & 3) * 16384;
    if (t + 3 < NT) { STAGE_A(t + 3); STAGE_B(t + 3); }
    // read all fragments of tile t (slot confirmed landed + barrier-sync'd)
    short8_t af[4][2], bf[2][2];
#pragma unroll
    for (int mi = 0; mi < 4; ++mi) {
      af[mi][0] = *(const short8_t*)(ldsb + sb + aoff + mi * 2048 + jt0);
      af[mi][1] = *(const short8_t*)(ldsb + sb + aoff + mi * 2048 + jt1);
    }
#pragma unroll
    for (int nj = 0; nj < 2; ++nj) {
      bf[nj][0] = *(const short8_t*)(ldsb + sb + boff + nj * 2048 + jt0);
      bf[nj][1] = *(const short8_t*)(ldsb + sb + boff + nj * 2048 + jt1);
    }
    // confirm stage(t+1) before the barrier that releases tile t+1's reads
    if (t < NT - 3) { VMCNT(8); }
    else if (t == NT - 3) { VMCNT(4); }
    else if (t == NT - 2) { VMCNT(0); }
    __builtin_amdgcn_s_barrier();
    asm volatile("s_waitcnt lgkmcnt(0)" ::: "memory");
    __builtin_amdgcn_sched_barrier(0);
    __builtin_amdgcn_s_setprio(1);
#pragma unroll
    for (int mi = 0; mi < 4; ++mi)
#pragma unroll
      for (int nj = 0; nj < 2; ++nj) {
        acc[mi][nj] = mfma32(af[mi][0], bf[nj][0], acc[mi][nj]);
        acc[mi][nj] = mfma32(af[mi][1], bf[nj][1], acc[mi][nj]);
      }
    __builtin_amdgcn_s_setprio(0);
    __builtin_amdgcn_s_barrier();
  }
#undef STAGE_A
#undef STAGE_B

  // ---------- epilogue (32x32 C/D map: row = base + (r&3)+8*(r>>2)+4*lh, col = base + l31) ----------
#pragma unroll
  for (int mi = 0; mi < 4; ++mi) {
#pragma unroll
    for (int nj = 0; nj < 2; ++nj) {
      if (MODE == 2) {
#pragma unroll
        for (int q = 0; q < 4; ++q) {
          int row0 = m0 + wm * 128 + mi * 32 + q * 8 + lh * 4;
          int col = n0 + wn * 64 + nj * 32 + l31;
          us4_t pk;
#pragma unroll
          for (int rr = 0; rr < 4; ++rr) pk[rr] = f2b(acc[mi][nj][q * 4 + rr]);
          *(us4_t*)((unsigned short*)Cout +
                    ((size_t)((row0 >> 11) * 1024 + col)) * 2048 + (row0 & 2047)) = pk;
        }
      } else {
#pragma unroll
        for (int r = 0; r < 16; ++r) {
          int row = m0 + wm * 128 + mi * 32 + (r & 3) + 8 * (r >> 2) + 4 * lh;
          int col = n0 + wn * 64 + nj * 32 + l31;
          if (MODE == 1)
            ((unsigned short*)Cout)[(size_t)row * ldc + col] = f2b(acc[mi][nj][r]);
          else
            ((float*)Cout)[(size_t)row * ldc + col] = acc[mi][nj][r];
        }
      }
    }
  }
}

// QKV: grid (24, 16). ct<16 -> Q, 16..19 -> K, 20..23 -> V(transposed store).
__global__ __launch_bounds__(512, 1) void gemm_qkv_kernel(
    const unsigned short* __restrict__ xb, const unsigned short* __restrict__ wqb,
    const unsigned short* __restrict__ wkb, const unsigned short* __restrict__ wvb,
    unsigned short* __restrict__ xq, unsigned short* __restrict__ xk,
    unsigned short* __restrict__ xvT) {
  __shared__ __align__(16) unsigned short lds[65536];  // 128 KiB, shared by all modes
  int ct = blockIdx.x, mt = blockIdx.y;
  if (ct < 16)      gemm256_core<1>(lds, xb, wqb, xq, mt * 256, ct * 256, 4096, 4096);
  else if (ct < 20) gemm256_core<1>(lds, xb, wkb, xk, mt * 256, (ct - 16) * 256, 4096, 1024);
  else              gemm256_core<2>(lds, xb, wvb, xvT, mt * 256, (ct - 20) * 256, 4096, 0);
}

__global__ __launch_bounds__(512, 1) void gemm_o_kernel(
    const unsigned short* __restrict__ ao, const unsigned short* __restrict__ wob,
    float* __restrict__ out) {
  __shared__ __align__(16) unsigned short lds[65536];
  gemm256_core<0>(lds, ao, wob, out, blockIdx.y * 256, blockIdx.x * 256, 4096, 4096);
}

// ---------------- RoPE ----------------
template <int NH>
__global__ void rope_kernel(unsigned short* __restrict__ p, const float* __restrict__ fr,
                            int nchunks) {
  for (int c = blockIdx.x * blockDim.x + threadIdx.x; c < nchunks;
       c += gridDim.x * blockDim.x) {
    size_t e = (size_t)c * 8;
    int f0 = (c & 15) * 4;
    int rest = (int)(e >> 7);
    int s = (rest / NH) & 2047;
    unsigned short* ptr = p + e;
    short8_t v = *(short8_t*)ptr;
    const float* cosp = fr + (size_t)s * 64 + f0;
    const float* sinp = cosp + 131072;
#pragma unroll
    for (int j = 0; j < 4; ++j) {
      float re = b2f((unsigned short)v[2 * j]);
      float im = b2f((unsigned short)v[2 * j + 1]);
      float cc = cosp[j], ss = sinp[j];
      v[2 * j]     = (short)f2b(re * cc - im * ss);
      v[2 * j + 1] = (short)f2b(re * ss + im * cc);
    }
    *(short8_t*)ptr = v;
  }
}

// ---------------- flash attention (Round-6 verified): 8 waves x 32 q-rows, 32x32 MFMA ----------------
__global__ __launch_bounds__(512, 2) void attn_kernel(
    const unsigned short* __restrict__ xq, const unsigned short* __restrict__ xk,
    const unsigned short* __restrict__ xvT, unsigned short* __restrict__ ao) {
  __shared__ __align__(16) unsigned char smem[56320];
  const int tid = threadIdx.x;
  const int wq = tid >> 6, lane = tid & 63;
  const int q31 = lane & 31, hi = lane >> 5;
  const int bx = 7 - (int)blockIdx.x;         // LPT: heaviest first
  const int h = blockIdx.y, b = blockIdx.z;
  const int hkv = h >> 2;
  const int q0 = bx * 256;
  const int a0 = q0 + wq * 32;
  const int ktmax_w = a0 >> 6;
  const int NT = bx * 4 + 4;

  const unsigned short* kbase = xk + ((size_t)(b * 2048) * 8 + hkv) * 128;
  const unsigned short* vtg = xvT + (size_t)(b * 1024 + hkv * 128) * 2048;

  const unsigned short* qrow = xq + ((size_t)(b * 2048 + a0 + q31) * 32 + h) * 128;
  short8_t qf[8];
#pragma unroll
  for (int st = 0; st < 8; ++st) qf[st] = *(const short8_t*)(qrow + st * 16 + hi * 8);

  const int c0 = tid, c1 = tid + 512;
  const int kg0 = (c0 >> 4) * 1024 + (c0 & 15) * 8;
  const int kg1 = (c1 >> 4) * 1024 + (c1 & 15) * 8;
  const int ka0 = (c0 >> 4) * 256 + (((c0 & 15) ^ ((c0 >> 4) & 7)) << 4);
  const int ka1 = (c1 >> 4) * 256 + (((c1 & 15) ^ ((c1 >> 4) & 7)) << 4);
  const int d0 = tid >> 3, kb0 = tid & 7, d1v = d0 + 64;
  const int vg0 = d0 * 2048 + kb0 * 8, vg1 = d1v * 2048 + kb0 * 8;
  const int va0 = d0 * 72 + kb0 * 8, va1 = d1v * 72 + kb0 * 8;

  unsigned short* Kb = (unsigned short*)(smem);
  unsigned short* VT = (unsigned short*)(smem + 16384);
  unsigned short* pp = (unsigned short*)(smem + 34816) + wq * 1280;
  unsigned short* prow = pp + q31 * 40;
  float* cl = (float*)(smem + 55296) + wq * 32;

  f32x16 o[4] = {};
  float m_run = -1e30f, l_run = 0.f;

  short8_t kr0 = *(const short8_t*)(kbase + kg0);
  short8_t kr1 = *(const short8_t*)(kbase + kg1);
  short8_t vr0 = *(const short8_t*)(vtg + vg0);
  short8_t vr1 = *(const short8_t*)(vtg + vg1);

  for (int kt = 0; kt < NT; ++kt) {
    *(short8_t*)((unsigned char*)Kb + ka0) = kr0;
    *(short8_t*)((unsigned char*)Kb + ka1) = kr1;
    *(short8_t*)(VT + va0) = vr0;
    *(short8_t*)(VT + va1) = vr1;
    __syncthreads();
    if (kt + 1 < NT) {
      const unsigned short* kg = kbase + (size_t)(kt + 1) * 65536;
      kr0 = *(const short8_t*)(kg + kg0);
      kr1 = *(const short8_t*)(kg + kg1);
      vr0 = *(const short8_t*)(vtg + vg0 + (kt + 1) * 64);
      vr1 = *(const short8_t*)(vtg + vg1 + (kt + 1) * 64);
    }

    if (kt <= ktmax_w) {
      const int r7 = (q31 & 7) << 4;
      f32x16 p0 = {}, p1 = {};
      __builtin_amdgcn_s_setprio(1);
#pragma unroll
      for (int st = 0; st < 8; ++st) {
        int cb = (((st * 2 + hi) << 4)) ^ r7;
        short8_t k0 = *(const short8_t*)((const unsigned char*)Kb + q31 * 256 + cb);
        short8_t k1 = *(const short8_t*)((const unsigned char*)Kb + (q31 + 32) * 256 + cb);
        p0 = mfma32(k0, qf[st], p0);
        p1 = mfma32(k1, qf[st], p1);
      }
      __builtin_amdgcn_s_setprio(0);

      if (kt == ktmax_w) {
        const int q = a0 + q31;
#pragma unroll
        for (int r = 0; r < 16; ++r) {
          int crow = (r & 3) + 8 * (r >> 2) + 4 * hi;
          int kgl = kt * 64 + crow;
          if (kgl > q) p0[r] = -1e30f;
          if (kgl + 32 > q) p1[r] = -1e30f;
        }
      }
      float mx = -1e30f;
#pragma unroll
      for (int r = 0; r < 16; ++r) mx = fmaxf(mx, fmaxf(p0[r], p1[r]));
      mx = fmaxf(mx, __shfl_xor(mx, 32));
      float mnew = fmaxf(m_run, mx);
      float corr = exp2f((m_run - mnew) * CEXP);
      m_run = mnew;
      float sum = 0.f;
#pragma unroll
      for (int r = 0; r < 16; ++r) {
        p0[r] = exp2f((p0[r] - mnew) * CEXP);
        p1[r] = exp2f((p1[r] - mnew) * CEXP);
        sum += p0[r] + p1[r];
      }
      sum += __shfl_xor(sum, 32);
      l_run = l_run * corr + sum;

      cl[q31] = corr;
      f32x4 cv0 = *(const f32x4*)(cl + hi * 4);
      f32x4 cv1 = *(const f32x4*)(cl + 8 + hi * 4);
      f32x4 cv2 = *(const f32x4*)(cl + 16 + hi * 4);
      f32x4 cv3 = *(const f32x4*)(cl + 24 + hi * 4);
#pragma unroll
      for (int db = 0; db < 4; ++db) {
#pragma unroll
        for (int r = 0; r < 4; ++r) {
          o[db][r]      *= cv0[r];
          o[db][4 + r]  *= cv1[r];
          o[db][8 + r]  *= cv2[r];
          o[db][12 + r] *= cv3[r];
        }
      }

#pragma unroll
      for (int u = 0; u < 4; ++u) {
        int2v w;
        w[0] = (int)((unsigned)f2b(p0[4 * u]) | ((unsigned)f2b(p0[4 * u + 1]) << 16));
        w[1] = (int)((unsigned)f2b(p0[4 * u + 2]) | ((unsigned)f2b(p0[4 * u + 3]) << 16));
        *(int2v*)(prow + u * 8 + hi * 4) = w;
      }
      {
        short8_t pa0 = *(const short8_t*)(prow + hi * 8);
        short8_t pa1 = *(const short8_t*)(prow + 16 + hi * 8);
        __builtin_amdgcn_s_setprio(1);
#pragma unroll
        for (int db = 0; db < 4; ++db) {
          const unsigned short* vtd = VT + (db * 32 + q31) * 72;
          short8_t vf0 = *(const short8_t*)(vtd + hi * 8);
          short8_t vf1 = *(const short8_t*)(vtd + 16 + hi * 8);
          o[db] = mfma32(pa0, vf0, o[db]);
          o[db] = mfma32(pa1, vf1, o[db]);
        }
        __builtin_amdgcn_s_setprio(0);
      }
#pragma unroll
      for (int u = 0; u < 4; ++u) {
        int2v w;
        w[0] = (int)((unsigned)f2b(p1[4 * u]) | ((unsigned)f2b(p1[4 * u + 1]) << 16));
        w[1] = (int)((unsigned)f2b(p1[4 * u + 2]) | ((unsigned)f2b(p1[4 * u + 3]) << 16));
        *(int2v*)(prow + u * 8 + hi * 4) = w;
      }
      {
        short8_t pa2 = *(const short8_t*)(prow + hi * 8);
        short8_t pa3 = *(const short8_t*)(prow + 16 + hi * 8);
        __builtin_amdgcn_s_setprio(1);
#pragma unroll
        for (int db = 0; db < 4; ++db) {
          const unsigned short* vtd = VT + (db * 32 + q31) * 72;
          short8_t vf2 = *(const short8_t*)(vtd + 32 + hi * 8);
          short8_t vf3 = *(const short8_t*)(vtd + 48 + hi * 8);
          o[db] = mfma32(pa2, vf2, o[db]);
          o[db] = mfma32(pa3, vf3, o[db]);
        }
        __builtin_amdgcn_s_setprio(0);
      }
    }
    __syncthreads();
  }

  cl[q31] = l_run;
  f32x4 lv0 = *(const f32x4*)(cl + hi * 4);
  f32x4 lv1 = *(const f32x4*)(cl + 8 + hi * 4);
  f32x4 lv2 = *(const f32x4*)(cl + 16 + hi * 4);
  f32x4 lv3 = *(const f32x4*)(cl + 24 + hi * 4);
  f32x4 iv0, iv1, iv2, iv3;
#pragma unroll
  for (int r = 0; r < 4; ++r) {
    iv0[r] = 1.0f / lv0[r]; iv1[r] = 1.0f / lv1[r];
    iv2[r] = 1.0f / lv2[r]; iv3[r] = 1.0f / lv3[r];
  }
  unsigned short* ob = ao + ((size_t)(b * 2048 + a0) * 32 + h) * 128;
#pragma unroll
  for (int db = 0; db < 4; ++db) {
#pragma unroll
    for (int r = 0; r < 16; ++r) {
      int crow = (r & 3) + 8 * (r >> 2) + 4 * hi;
      float iv = (r < 4) ? iv0[r & 3] : (r < 8) ? iv1[r & 3] : (r < 12) ? iv2[r & 3] : iv3[r & 3];
      ob[(size_t)crow * 4096 + db * 32 + q31] = f2b(o[db][r] * iv);
    }
  }
}

// ---------------- launch ----------------
extern "C" void kernel_launch(void* const* d_in, const int* in_sizes, int n_in,
                              void* d_out, int out_size, void* d_ws, size_t ws_size,
                              hipStream_t stream) {
  const float* x  = (const float*)d_in[0];
  const float* wq = (const float*)d_in[1];
  const float* wk = (const float*)d_in[2];
  const float* wv = (const float*)d_in[3];
  const float* wo = (const float*)d_in[4];
  const float* fr = (const float*)d_in[7];
  float* out = (float*)d_out;

  char* ws = (char*)d_ws;
  unsigned short* xb  = (unsigned short*)(ws);               // 33.5MB; reused as ao
  unsigned short* wqb = (unsigned short*)(ws + 33554432);    // 33.5MB; reused as wob
  unsigned short* wkb = (unsigned short*)(ws + 67108864);    // 8.4MB
  unsigned short* wvb = (unsigned short*)(ws + 75497472);    // 8.4MB
  unsigned short* xq  = (unsigned short*)(ws + 83886080);    // 33.5MB
  unsigned short* xk  = (unsigned short*)(ws + 117440512);   // 8.4MB
  unsigned short* xvT = (unsigned short*)(ws + 125829120);   // 8.4MB (total 128MiB)
  unsigned short* ao  = xb;
  unsigned short* wob = wqb;

  dim3 blk(256);
  cvt_kernel<<<dim3(1024), blk, 0, stream>>>(x,  xb,  16777216 / 4);
  cvt_kernel<<<dim3(1024), blk, 0, stream>>>(wq, wqb, 16777216 / 4);
  cvt_kernel<<<dim3(512),  blk, 0, stream>>>(wk, wkb, 4194304 / 4);
  cvt_kernel<<<dim3(512),  blk, 0, stream>>>(wv, wvb, 4194304 / 4);

  gemm_qkv_kernel<<<dim3(24, 16), dim3(512), 0, stream>>>(xb, wqb, wkb, wvb, xq, xk, xvT);

  rope_kernel<32><<<dim3(2048), blk, 0, stream>>>(xq, fr, 2097152);
  rope_kernel<8><<<dim3(512),  blk, 0, stream>>>(xk, fr, 524288);

  cvt_kernel<<<dim3(1024), blk, 0, stream>>>(wo, wob, 16777216 / 4);

  attn_kernel<<<dim3(8, 32, 2), dim3(512), 0, stream>>>(xq, xk, xvT, ao);

  gemm_o_kernel<<<dim3(16, 16), dim3(512), 0, stream>>>(ao, wob, out);
}

// Round 15
// 622.882 us; speedup vs baseline: 1.0961x; 1.0961x over previous
//
#include <hip/hip_runtime.h>

typedef __bf16 bf16x8 __attribute__((ext_vector_type(8)));
typedef short short8_t __attribute__((ext_vector_type(8)));
typedef float f32x4 __attribute__((ext_vector_type(4)));
typedef float f32x16 __attribute__((ext_vector_type(16)));
typedef int int2v __attribute__((ext_vector_type(2)));
typedef unsigned short us4_t __attribute__((ext_vector_type(4)));

#define SCALE 0.08838834764831845f  // 1/sqrt(128)
#define CEXP 0.1275179f             // SCALE * log2(e)

#define VMCNT(n) asm volatile("s_waitcnt vmcnt(" #n ")" ::: "memory")

__device__ __forceinline__ float b2f(unsigned short u) {
  union { unsigned int i; float f; } v; v.i = ((unsigned int)u) << 16; return v.f;
}
__device__ __forceinline__ unsigned short f2b(float f) {
  union { float f; unsigned int i; } v; v.f = f;
  unsigned int r = v.i + 0x7fffu + ((v.i >> 16) & 1u);
  return (unsigned short)(r >> 16);
}

__device__ __forceinline__ f32x4 mfma16(short8_t a, short8_t b, f32x4 c) {
  return __builtin_amdgcn_mfma_f32_16x16x32_bf16(
      __builtin_bit_cast(bf16x8, a), __builtin_bit_cast(bf16x8, b), c, 0, 0, 0);
}
__device__ __forceinline__ f32x16 mfma32(short8_t a, short8_t b, f32x16 c) {
  return __builtin_amdgcn_mfma_f32_32x32x16_bf16(
      __builtin_bit_cast(bf16x8, a), __builtin_bit_cast(bf16x8, b), c, 0, 0, 0);
}

typedef __attribute__((address_space(1))) const void gas_t;
typedef __attribute__((address_space(3))) void las_t;
__device__ __forceinline__ void gload16(const void* g, void* l) {
  __builtin_amdgcn_global_load_lds((gas_t*)g, (las_t*)l, 16, 0, 0);
}

// ---------------- fp32 -> bf16 convert ----------------
__global__ void cvt_kernel(const float* __restrict__ src, unsigned short* __restrict__ dst, int n4) {
  for (int i = blockIdx.x * blockDim.x + threadIdx.x; i < n4; i += gridDim.x * blockDim.x) {
    f32x4 v = *(const f32x4*)(src + (size_t)i * 4);
    us4_t o;
    o[0] = f2b(v[0]); o[1] = f2b(v[1]); o[2] = f2b(v[2]); o[3] = f2b(v[3]);
    *(us4_t*)(dst + (size_t)i * 4) = o;
  }
}

// ============ 256x256 counted-vmcnt pipelined GEMM core (R12, verified) ============
// BK=32, 4 LDS slots (stage lead 3), 8 waves (2M x 4N), ONE phase per K-tile.
// MODE: 0 = f32 out, 1 = bf16 out
template <int MODE>
__device__ __forceinline__ void gemm256_core(
    unsigned short* __restrict__ lds,
    const unsigned short* __restrict__ A, const unsigned short* __restrict__ Bt,
    void* __restrict__ Cout, int m0, int n0, int K, int ldc) {
  const int tid = threadIdx.x;
  const int wid = tid >> 6, lane = tid & 63;
  const int ln = lane & 15, lg = lane >> 4;
  const int wm = wid >> 2, wn = wid & 3;
  const int NT = K >> 5;

  const int sr0 = wid * 16 + (lane >> 2);
  const int sr1 = 128 + sr0;
  const int sj0 = ((lane & 3) ^ ((sr0 >> 1) & 3)) * 8;
  const int sj1 = ((lane & 3) ^ ((sr1 >> 1) & 3)) * 8;
  const unsigned short* gA0 = A + (size_t)(m0 + sr0) * K + sj0;
  const unsigned short* gA1 = A + (size_t)(m0 + sr1) * K + sj1;
  const unsigned short* gB0 = Bt + (size_t)(n0 + sr0) * K + sj0;
  const unsigned short* gB1 = Bt + (size_t)(n0 + sr1) * K + sj1;
  unsigned short* dA = lds + wid * 512;
  unsigned short* dB = lds + 32768 + wid * 512;

  const int swz = (ln >> 1) & 3;
  const int jA = (lg ^ swz) << 4;
  const unsigned char* ldsb = (const unsigned char*)lds;
  const int aoff = (wm * 128 + ln) * 64 + jA;
  const int boff = 65536 + (wn * 64 + ln) * 64 + jA;

  f32x4 acc[8][4] = {};

#define STAGE_A(t_) { int s_ = (t_) & 3; int k0_ = (t_) << 5; \
    gload16(gA0 + k0_, dA + s_ * 8192); \
    gload16(gA1 + k0_, dA + s_ * 8192 + 4096); }
#define STAGE_B(t_) { int s_ = (t_) & 3; int k0_ = (t_) << 5; \
    gload16(gB0 + k0_, dB + s_ * 8192); \
    gload16(gB1 + k0_, dB + s_ * 8192 + 4096); }

  STAGE_A(0); STAGE_B(0);
  STAGE_A(1); STAGE_B(1);
  STAGE_A(2); STAGE_B(2);
  VMCNT(8);
  __builtin_amdgcn_s_barrier();

  for (int t = 0; t < NT; ++t) {
    const int sb = (t & 3) * 16384;
    if (t + 3 < NT) { STAGE_A(t + 3); STAGE_B(t + 3); }
    short8_t af[8], bf[4];
#pragma unroll
    for (int mi = 0; mi < 8; ++mi)
      af[mi] = *(const short8_t*)(ldsb + sb + aoff + mi * 1024);
#pragma unroll
    for (int nj = 0; nj < 4; ++nj)
      bf[nj] = *(const short8_t*)(ldsb + sb + boff + nj * 1024);
    if (t < NT - 3) { VMCNT(8); }
    else if (t == NT - 3) { VMCNT(4); }
    else if (t == NT - 2) { VMCNT(0); }
    __builtin_amdgcn_s_barrier();
    asm volatile("s_waitcnt lgkmcnt(0)" ::: "memory");
    __builtin_amdgcn_sched_barrier(0);
    __builtin_amdgcn_s_setprio(1);
#pragma unroll
    for (int mi = 0; mi < 8; ++mi)
#pragma unroll
      for (int nj = 0; nj < 4; ++nj)
        acc[mi][nj] = mfma16(af[mi], bf[nj], acc[mi][nj]);
    __builtin_amdgcn_s_setprio(0);
    __builtin_amdgcn_s_barrier();
  }
#undef STAGE_A
#undef STAGE_B

#pragma unroll
  for (int mi = 0; mi < 8; ++mi) {
#pragma unroll
    for (int nj = 0; nj < 4; ++nj) {
#pragma unroll
      for (int r = 0; r < 4; ++r) {
        int row = m0 + wm * 128 + mi * 16 + lg * 4 + r;
        int col = n0 + wn * 64 + nj * 16 + ln;
        if (MODE == 1)
          ((unsigned short*)Cout)[(size_t)row * ldc + col] = f2b(acc[mi][nj][r]);
        else
          ((float*)Cout)[(size_t)row * ldc + col] = acc[mi][nj][r];
      }
    }
  }
}

// ============ 128x128 GEMM core (R6, verified) — for K/V projections ============
// MODE: 1 = bf16 out, 2 = bf16 transposed-V out
template <int MODE>
__device__ __forceinline__ void gemm128(unsigned short* __restrict__ ldsbuf,
                                        const unsigned short* __restrict__ A,
                                        const unsigned short* __restrict__ Bt,
                                        void* __restrict__ Cout,
                                        int m0, int n0, int K, int ldc) {
  unsigned short* As = ldsbuf;             // 128*32 shorts
  unsigned short* Bs = ldsbuf + 4096;      // 128*32 shorts
  const int tid = threadIdx.x;
  const int wave = tid >> 6, lane = tid & 63;
  const int ln = lane & 15, g = lane >> 4;
  const int wm = (wave >> 1) * 64, wn = (wave & 1) * 64;

  const int rA0 = wave * 16 + (lane >> 2);
  const int rA1 = 64 + wave * 16 + (lane >> 2);
  const int colx = (lane & 3) * 8;
  const unsigned short* gA0 = A + (size_t)(m0 + rA0) * K + colx;
  const unsigned short* gA1 = A + (size_t)(m0 + rA1) * K + colx;
  const unsigned short* gB0 = Bt + (size_t)(n0 + rA0) * K + colx;
  const unsigned short* gB1 = Bt + (size_t)(n0 + rA1) * K + colx;
  unsigned short* lA0 = As + wave * 512;
  unsigned short* lA1 = As + 2048 + wave * 512;
  unsigned short* lB0 = Bs + wave * 512;
  unsigned short* lB1 = Bs + 2048 + wave * 512;

  f32x4 acc[4][4] = {};

  for (int k0 = 0; k0 < K; k0 += 32) {
    gload16(gA0 + k0, lA0);
    gload16(gA1 + k0, lA1);
    gload16(gB0 + k0, lB0);
    gload16(gB1 + k0, lB1);
    __syncthreads();
    short8_t a[4], b[4];
#pragma unroll
    for (int i = 0; i < 4; ++i)
      a[i] = *(const short8_t*)(As + (wm + i * 16 + ln) * 32 + g * 8);
#pragma unroll
    for (int j = 0; j < 4; ++j)
      b[j] = *(const short8_t*)(Bs + (wn + j * 16 + ln) * 32 + g * 8);
#pragma unroll
    for (int i = 0; i < 4; ++i)
#pragma unroll
      for (int j = 0; j < 4; ++j)
        acc[i][j] = mfma16(a[i], b[j], acc[i][j]);
    __syncthreads();
  }

#pragma unroll
  for (int i = 0; i < 4; ++i) {
#pragma unroll
    for (int j = 0; j < 4; ++j) {
      if (MODE == 2) {
        int row0 = m0 + wm + i * 16 + g * 4;
        int col = n0 + wn + j * 16 + ln;
        us4_t pk;
#pragma unroll
        for (int r = 0; r < 4; ++r) pk[r] = f2b(acc[i][j][r]);
        *(us4_t*)((unsigned short*)Cout +
                  ((size_t)((row0 >> 11) * 1024 + col)) * 2048 + (row0 & 2047)) = pk;
      } else {
#pragma unroll
        for (int r = 0; r < 4; ++r) {
          int row = m0 + wm + i * 16 + g * 4 + r;
          int col = n0 + wn + j * 16 + ln;
          ((unsigned short*)Cout)[(size_t)row * ldc + col] = f2b(acc[i][j][r]);
        }
      }
    }
  }
}

// Q projection: grid (16,16), 256 tiles exactly = 1 full round of 256 CUs.
__global__ __launch_bounds__(512, 1) void gemm_q_kernel(
    const unsigned short* __restrict__ xb, const unsigned short* __restrict__ wqb,
    unsigned short* __restrict__ xq) {
  __shared__ __align__(16) unsigned short lds[65536];
  gemm256_core<1>(lds, xb, wqb, xq, blockIdx.y * 256, blockIdx.x * 256, 4096, 4096);
}

// K/V projections: grid (16, 32), 128^2 tiles, high occupancy (16 KB LDS).
__global__ __launch_bounds__(256) void gemm_kv_kernel(
    const unsigned short* __restrict__ xb, const unsigned short* __restrict__ wkb,
    const unsigned short* __restrict__ wvb, unsigned short* __restrict__ xk,
    unsigned short* __restrict__ xvT) {
  __shared__ __align__(16) unsigned short lds[8192];  // 16 KiB
  int bx = blockIdx.x, by = blockIdx.y;
  if (bx < 8) gemm128<1>(lds, xb, wkb, xk, by * 128, bx * 128, 4096, 1024);
  else        gemm128<2>(lds, xb, wvb, xvT, by * 128, (bx - 8) * 128, 4096, 0);
}

__global__ __launch_bounds__(512, 1) void gemm_o_kernel(
    const unsigned short* __restrict__ ao, const unsigned short* __restrict__ wob,
    float* __restrict__ out) {
  __shared__ __align__(16) unsigned short lds[65536];
  gemm256_core<0>(lds, ao, wob, out, blockIdx.y * 256, blockIdx.x * 256, 4096, 4096);
}

// ---------------- RoPE ----------------
template <int NH>
__global__ void rope_kernel(unsigned short* __restrict__ p, const float* __restrict__ fr,
                            int nchunks) {
  for (int c = blockIdx.x * blockDim.x + threadIdx.x; c < nchunks;
       c += gridDim.x * blockDim.x) {
    size_t e = (size_t)c * 8;
    int f0 = (c & 15) * 4;
    int rest = (int)(e >> 7);
    int s = (rest / NH) & 2047;
    unsigned short* ptr = p + e;
    short8_t v = *(short8_t*)ptr;
    const float* cosp = fr + (size_t)s * 64 + f0;
    const float* sinp = cosp + 131072;
#pragma unroll
    for (int j = 0; j < 4; ++j) {
      float re = b2f((unsigned short)v[2 * j]);
      float im = b2f((unsigned short)v[2 * j + 1]);
      float cc = cosp[j], ss = sinp[j];
      v[2 * j]     = (short)f2b(re * cc - im * ss);
      v[2 * j + 1] = (short)f2b(re * ss + im * cc);
    }
    *(short8_t*)ptr = v;
  }
}

// ---------------- flash attention (Round-6 verified): 8 waves x 32 q-rows, 32x32 MFMA ----------------
__global__ __launch_bounds__(512, 2) void attn_kernel(
    const unsigned short* __restrict__ xq, const unsigned short* __restrict__ xk,
    const unsigned short* __restrict__ xvT, unsigned short* __restrict__ ao) {
  __shared__ __align__(16) unsigned char smem[56320];
  const int tid = threadIdx.x;
  const int wq = tid >> 6, lane = tid & 63;
  const int q31 = lane & 31, hi = lane >> 5;
  const int bx = 7 - (int)blockIdx.x;         // LPT: heaviest first
  const int h = blockIdx.y, b = blockIdx.z;
  const int hkv = h >> 2;
  const int q0 = bx * 256;
  const int a0 = q0 + wq * 32;
  const int ktmax_w = a0 >> 6;
  const int NT = bx * 4 + 4;

  const unsigned short* kbase = xk + ((size_t)(b * 2048) * 8 + hkv) * 128;
  const unsigned short* vtg = xvT + (size_t)(b * 1024 + hkv * 128) * 2048;

  const unsigned short* qrow = xq + ((size_t)(b * 2048 + a0 + q31) * 32 + h) * 128;
  short8_t qf[8];
#pragma unroll
  for (int st = 0; st < 8; ++st) qf[st] = *(const short8_t*)(qrow + st * 16 + hi * 8);

  const int c0 = tid, c1 = tid + 512;
  const int kg0 = (c0 >> 4) * 1024 + (c0 & 15) * 8;
  const int kg1 = (c1 >> 4) * 1024 + (c1 & 15) * 8;
  const int ka0 = (c0 >> 4) * 256 + (((c0 & 15) ^ ((c0 >> 4) & 7)) << 4);
  const int ka1 = (c1 >> 4) * 256 + (((c1 & 15) ^ ((c1 >> 4) & 7)) << 4);
  const int d0 = tid >> 3, kb0 = tid & 7, d1v = d0 + 64;
  const int vg0 = d0 * 2048 + kb0 * 8, vg1 = d1v * 2048 + kb0 * 8;
  const int va0 = d0 * 72 + kb0 * 8, va1 = d1v * 72 + kb0 * 8;

  unsigned short* Kb = (unsigned short*)(smem);
  unsigned short* VT = (unsigned short*)(smem + 16384);
  unsigned short* pp = (unsigned short*)(smem + 34816) + wq * 1280;
  unsigned short* prow = pp + q31 * 40;
  float* cl = (float*)(smem + 55296) + wq * 32;

  f32x16 o[4] = {};
  float m_run = -1e30f, l_run = 0.f;

  short8_t kr0 = *(const short8_t*)(kbase + kg0);
  short8_t kr1 = *(const short8_t*)(kbase + kg1);
  short8_t vr0 = *(const short8_t*)(vtg + vg0);
  short8_t vr1 = *(const short8_t*)(vtg + vg1);

  for (int kt = 0; kt < NT; ++kt) {
    *(short8_t*)((unsigned char*)Kb + ka0) = kr0;
    *(short8_t*)((unsigned char*)Kb + ka1) = kr1;
    *(short8_t*)(VT + va0) = vr0;
    *(short8_t*)(VT + va1) = vr1;
    __syncthreads();
    if (kt + 1 < NT) {
      const unsigned short* kg = kbase + (size_t)(kt + 1) * 65536;
      kr0 = *(const short8_t*)(kg + kg0);
      kr1 = *(const short8_t*)(kg + kg1);
      vr0 = *(const short8_t*)(vtg + vg0 + (kt + 1) * 64);
      vr1 = *(const short8_t*)(vtg + vg1 + (kt + 1) * 64);
    }

    if (kt <= ktmax_w) {
      const int r7 = (q31 & 7) << 4;
      f32x16 p0 = {}, p1 = {};
      __builtin_amdgcn_s_setprio(1);
#pragma unroll
      for (int st = 0; st < 8; ++st) {
        int cb = (((st * 2 + hi) << 4)) ^ r7;
        short8_t k0 = *(const short8_t*)((const unsigned char*)Kb + q31 * 256 + cb);
        short8_t k1 = *(const short8_t*)((const unsigned char*)Kb + (q31 + 32) * 256 + cb);
        p0 = mfma32(k0, qf[st], p0);
        p1 = mfma32(k1, qf[st], p1);
      }
      __builtin_amdgcn_s_setprio(0);

      if (kt == ktmax_w) {
        const int q = a0 + q31;
#pragma unroll
        for (int r = 0; r < 16; ++r) {
          int crow = (r & 3) + 8 * (r >> 2) + 4 * hi;
          int kgl = kt * 64 + crow;
          if (kgl > q) p0[r] = -1e30f;
          if (kgl + 32 > q) p1[r] = -1e30f;
        }
      }
      float mx = -1e30f;
#pragma unroll
      for (int r = 0; r < 16; ++r) mx = fmaxf(mx, fmaxf(p0[r], p1[r]));
      mx = fmaxf(mx, __shfl_xor(mx, 32));
      float mnew = fmaxf(m_run, mx);
      float corr = exp2f((m_run - mnew) * CEXP);
      m_run = mnew;
      float sum = 0.f;
#pragma unroll
      for (int r = 0; r < 16; ++r) {
        p0[r] = exp2f((p0[r] - mnew) * CEXP);
        p1[r] = exp2f((p1[r] - mnew) * CEXP);
        sum += p0[r] + p1[r];
      }
      sum += __shfl_xor(sum, 32);
      l_run = l_run * corr + sum;

      cl[q31] = corr;
      f32x4 cv0 = *(const f32x4*)(cl + hi * 4);
      f32x4 cv1 = *(const f32x4*)(cl + 8 + hi * 4);
      f32x4 cv2 = *(const f32x4*)(cl + 16 + hi * 4);
      f32x4 cv3 = *(const f32x4*)(cl + 24 + hi * 4);
#pragma unroll
      for (int db = 0; db < 4; ++db) {
#pragma unroll
        for (int r = 0; r < 4; ++r) {
          o[db][r]      *= cv0[r];
          o[db][4 + r]  *= cv1[r];
          o[db][8 + r]  *= cv2[r];
          o[db][12 + r] *= cv3[r];
        }
      }

#pragma unroll
      for (int u = 0; u < 4; ++u) {
        int2v w;
        w[0] = (int)((unsigned)f2b(p0[4 * u]) | ((unsigned)f2b(p0[4 * u + 1]) << 16));
        w[1] = (int)((unsigned)f2b(p0[4 * u + 2]) | ((unsigned)f2b(p0[4 * u + 3]) << 16));
        *(int2v*)(prow + u * 8 + hi * 4) = w;
      }
      {
        short8_t pa0 = *(const short8_t*)(prow + hi * 8);
        short8_t pa1 = *(const short8_t*)(prow + 16 + hi * 8);
        __builtin_amdgcn_s_setprio(1);
#pragma unroll
        for (int db = 0; db < 4; ++db) {
          const unsigned short* vtd = VT + (db * 32 + q31) * 72;
          short8_t vf0 = *(const short8_t*)(vtd + hi * 8);
          short8_t vf1 = *(const short8_t*)(vtd + 16 + hi * 8);
          o[db] = mfma32(pa0, vf0, o[db]);
          o[db] = mfma32(pa1, vf1, o[db]);
        }
        __builtin_amdgcn_s_setprio(0);
      }
#pragma unroll
      for (int u = 0; u < 4; ++u) {
        int2v w;
        w[0] = (int)((unsigned)f2b(p1[4 * u]) | ((unsigned)f2b(p1[4 * u + 1]) << 16));
        w[1] = (int)((unsigned)f2b(p1[4 * u + 2]) | ((unsigned)f2b(p1[4 * u + 3]) << 16));
        *(int2v*)(prow + u * 8 + hi * 4) = w;
      }
      {
        short8_t pa2 = *(const short8_t*)(prow + hi * 8);
        short8_t pa3 = *(const short8_t*)(prow + 16 + hi * 8);
        __builtin_amdgcn_s_setprio(1);
#pragma unroll
        for (int db = 0; db < 4; ++db) {
          const unsigned short* vtd = VT + (db * 32 + q31) * 72;
          short8_t vf2 = *(const short8_t*)(vtd + 32 + hi * 8);
          short8_t vf3 = *(const short8_t*)(vtd + 48 + hi * 8);
          o[db] = mfma32(pa2, vf2, o[db]);
          o[db] = mfma32(pa3, vf3, o[db]);
        }
        __builtin_amdgcn_s_setprio(0);
      }
    }
    __syncthreads();
  }

  cl[q31] = l_run;
  f32x4 lv0 = *(const f32x4*)(cl + hi * 4);
  f32x4 lv1 = *(const f32x4*)(cl + 8 + hi * 4);
  f32x4 lv2 = *(const f32x4*)(cl + 16 + hi * 4);
  f32x4 lv3 = *(const f32x4*)(cl + 24 + hi * 4);
  f32x4 iv0, iv1, iv2, iv3;
#pragma unroll
  for (int r = 0; r < 4; ++r) {
    iv0[r] = 1.0f / lv0[r]; iv1[r] = 1.0f / lv1[r];
    iv2[r] = 1.0f / lv2[r]; iv3[r] = 1.0f / lv3[r];
  }
  unsigned short* ob = ao + ((size_t)(b * 2048 + a0) * 32 + h) * 128;
#pragma unroll
  for (int db = 0; db < 4; ++db) {
#pragma unroll
    for (int r = 0; r < 16; ++r) {
      int crow = (r & 3) + 8 * (r >> 2) + 4 * hi;
      float iv = (r < 4) ? iv0[r & 3] : (r < 8) ? iv1[r & 3] : (r < 12) ? iv2[r & 3] : iv3[r & 3];
      ob[(size_t)crow * 4096 + db * 32 + q31] = f2b(o[db][r] * iv);
    }
  }
}

// ---------------- launch ----------------
extern "C" void kernel_launch(void* const* d_in, const int* in_sizes, int n_in,
                              void* d_out, int out_size, void* d_ws, size_t ws_size,
                              hipStream_t stream) {
  const float* x  = (const float*)d_in[0];
  const float* wq = (const float*)d_in[1];
  const float* wk = (const float*)d_in[2];
  const float* wv = (const float*)d_in[3];
  const float* wo = (const float*)d_in[4];
  const float* fr = (const float*)d_in[7];
  float* out = (float*)d_out;

  char* ws = (char*)d_ws;
  unsigned short* xb  = (unsigned short*)(ws);               // 33.5MB; reused as ao
  unsigned short* wqb = (unsigned short*)(ws + 33554432);    // 33.5MB; reused as wob
  unsigned short* wkb = (unsigned short*)(ws + 67108864);    // 8.4MB
  unsigned short* wvb = (unsigned short*)(ws + 75497472);    // 8.4MB
  unsigned short* xq  = (unsigned short*)(ws + 83886080);    // 33.5MB
  unsigned short* xk  = (unsigned short*)(ws + 117440512);   // 8.4MB
  unsigned short* xvT = (unsigned short*)(ws + 125829120);   // 8.4MB (total 128MiB)
  unsigned short* ao  = xb;
  unsigned short* wob = wqb;

  dim3 blk(256);
  cvt_kernel<<<dim3(1024), blk, 0, stream>>>(x,  xb,  16777216 / 4);
  cvt_kernel<<<dim3(1024), blk, 0, stream>>>(wq, wqb, 16777216 / 4);
  cvt_kernel<<<dim3(512),  blk, 0, stream>>>(wk, wkb, 4194304 / 4);
  cvt_kernel<<<dim3(512),  blk, 0, stream>>>(wv, wvb, 4194304 / 4);

  gemm_q_kernel<<<dim3(16, 16), dim3(512), 0, stream>>>(xb, wqb, xq);
  gemm_kv_kernel<<<dim3(16, 32), dim3(256), 0, stream>>>(xb, wkb, wvb, xk, xvT);

  rope_kernel<32><<<dim3(2048), blk, 0, stream>>>(xq, fr, 2097152);
  rope_kernel<8><<<dim3(512),  blk, 0, stream>>>(xk, fr, 524288);

  cvt_kernel<<<dim3(1024), blk, 0, stream>>>(wo, wob, 16777216 / 4);

  attn_kernel<<<dim3(8, 32, 2), dim3(512), 0, stream>>>(xq, xk, xvT, ao);

  gemm_o_kernel<<<dim3(16, 16), dim3(512), 0, stream>>>(ao, wob, out);
}

// Round 16
// 543.564 us; speedup vs baseline: 1.2560x; 1.1459x over previous
//
#include <hip/hip_runtime.h>

typedef __bf16 bf16x8 __attribute__((ext_vector_type(8)));
typedef short short8_t __attribute__((ext_vector_type(8)));
typedef float f32x4 __attribute__((ext_vector_type(4)));
typedef float f32x16 __attribute__((ext_vector_type(16)));
typedef int int2v __attribute__((ext_vector_type(2)));
typedef unsigned short us4_t __attribute__((ext_vector_type(4)));

#define SCALE 0.08838834764831845f  // 1/sqrt(128)
#define CEXP 0.1275179f             // SCALE * log2(e)

#define VMCNT(n) asm volatile("s_waitcnt vmcnt(" #n ")" ::: "memory")

__device__ __forceinline__ float b2f(unsigned short u) {
  union { unsigned int i; float f; } v; v.i = ((unsigned int)u) << 16; return v.f;
}
__device__ __forceinline__ unsigned short f2b(float f) {
  union { float f; unsigned int i; } v; v.f = f;
  unsigned int r = v.i + 0x7fffu + ((v.i >> 16) & 1u);
  return (unsigned short)(r >> 16);
}

__device__ __forceinline__ f32x4 mfma16(short8_t a, short8_t b, f32x4 c) {
  return __builtin_amdgcn_mfma_f32_16x16x32_bf16(
      __builtin_bit_cast(bf16x8, a), __builtin_bit_cast(bf16x8, b), c, 0, 0, 0);
}
__device__ __forceinline__ f32x16 mfma32(short8_t a, short8_t b, f32x16 c) {
  return __builtin_amdgcn_mfma_f32_32x32x16_bf16(
      __builtin_bit_cast(bf16x8, a), __builtin_bit_cast(bf16x8, b), c, 0, 0, 0);
}

typedef __attribute__((address_space(1))) const void gas_t;
typedef __attribute__((address_space(3))) void las_t;
__device__ __forceinline__ void gload16(const void* g, void* l) {
  __builtin_amdgcn_global_load_lds((gas_t*)g, (las_t*)l, 16, 0, 0);
}

// ---------------- fp32 -> bf16 convert ----------------
__global__ void cvt_kernel(const float* __restrict__ src, unsigned short* __restrict__ dst, int n4) {
  for (int i = blockIdx.x * blockDim.x + threadIdx.x; i < n4; i += gridDim.x * blockDim.x) {
    f32x4 v = *(const f32x4*)(src + (size_t)i * 4);
    us4_t o;
    o[0] = f2b(v[0]); o[1] = f2b(v[1]); o[2] = f2b(v[2]); o[3] = f2b(v[3]);
    *(us4_t*)(dst + (size_t)i * 4) = o;
  }
}

// ============ 256x256 counted-vmcnt pipelined GEMM core (R12, verified) ============
// BK=32, 4 LDS slots (stage lead 3), 8 waves (2M x 4N), ONE phase per K-tile.
// MODE: 0 = f32 out, 1 = bf16 out
template <int MODE>
__device__ __forceinline__ void gemm256_core(
    unsigned short* __restrict__ lds,
    const unsigned short* __restrict__ A, const unsigned short* __restrict__ Bt,
    void* __restrict__ Cout, int m0, int n0, int K, int ldc) {
  const int tid = threadIdx.x;
  const int wid = tid >> 6, lane = tid & 63;
  const int ln = lane & 15, lg = lane >> 4;
  const int wm = wid >> 2, wn = wid & 3;
  const int NT = K >> 5;

  const int sr0 = wid * 16 + (lane >> 2);
  const int sr1 = 128 + sr0;
  const int sj0 = ((lane & 3) ^ ((sr0 >> 1) & 3)) * 8;
  const int sj1 = ((lane & 3) ^ ((sr1 >> 1) & 3)) * 8;
  const unsigned short* gA0 = A + (size_t)(m0 + sr0) * K + sj0;
  const unsigned short* gA1 = A + (size_t)(m0 + sr1) * K + sj1;
  const unsigned short* gB0 = Bt + (size_t)(n0 + sr0) * K + sj0;
  const unsigned short* gB1 = Bt + (size_t)(n0 + sr1) * K + sj1;
  unsigned short* dA = lds + wid * 512;
  unsigned short* dB = lds + 32768 + wid * 512;

  const int swz = (ln >> 1) & 3;
  const int jA = (lg ^ swz) << 4;
  const unsigned char* ldsb = (const unsigned char*)lds;
  const int aoff = (wm * 128 + ln) * 64 + jA;
  const int boff = 65536 + (wn * 64 + ln) * 64 + jA;

  f32x4 acc[8][4] = {};

#define STAGE_A(t_) { int s_ = (t_) & 3; int k0_ = (t_) << 5; \
    gload16(gA0 + k0_, dA + s_ * 8192); \
    gload16(gA1 + k0_, dA + s_ * 8192 + 4096); }
#define STAGE_B(t_) { int s_ = (t_) & 3; int k0_ = (t_) << 5; \
    gload16(gB0 + k0_, dB + s_ * 8192); \
    gload16(gB1 + k0_, dB + s_ * 8192 + 4096); }

  STAGE_A(0); STAGE_B(0);
  STAGE_A(1); STAGE_B(1);
  STAGE_A(2); STAGE_B(2);
  VMCNT(8);
  __builtin_amdgcn_s_barrier();

  for (int t = 0; t < NT; ++t) {
    const int sb = (t & 3) * 16384;
    if (t + 3 < NT) { STAGE_A(t + 3); STAGE_B(t + 3); }
    short8_t af[8], bf[4];
#pragma unroll
    for (int mi = 0; mi < 8; ++mi)
      af[mi] = *(const short8_t*)(ldsb + sb + aoff + mi * 1024);
#pragma unroll
    for (int nj = 0; nj < 4; ++nj)
      bf[nj] = *(const short8_t*)(ldsb + sb + boff + nj * 1024);
    if (t < NT - 3) { VMCNT(8); }
    else if (t == NT - 3) { VMCNT(4); }
    else if (t == NT - 2) { VMCNT(0); }
    __builtin_amdgcn_s_barrier();
    asm volatile("s_waitcnt lgkmcnt(0)" ::: "memory");
    __builtin_amdgcn_sched_barrier(0);
    __builtin_amdgcn_s_setprio(1);
#pragma unroll
    for (int mi = 0; mi < 8; ++mi)
#pragma unroll
      for (int nj = 0; nj < 4; ++nj)
        acc[mi][nj] = mfma16(af[mi], bf[nj], acc[mi][nj]);
    __builtin_amdgcn_s_setprio(0);
    __builtin_amdgcn_s_barrier();
  }
#undef STAGE_A
#undef STAGE_B

#pragma unroll
  for (int mi = 0; mi < 8; ++mi) {
#pragma unroll
    for (int nj = 0; nj < 4; ++nj) {
#pragma unroll
      for (int r = 0; r < 4; ++r) {
        int row = m0 + wm * 128 + mi * 16 + lg * 4 + r;
        int col = n0 + wn * 64 + nj * 16 + ln;
        if (MODE == 1)
          ((unsigned short*)Cout)[(size_t)row * ldc + col] = f2b(acc[mi][nj][r]);
        else
          ((float*)Cout)[(size_t)row * ldc + col] = acc[mi][nj][r];
      }
    }
  }
}

// ============ 128x128 GEMM core (R6, verified) — for K/V projections ============
// MODE: 1 = bf16 out, 2 = bf16 transposed-V out
template <int MODE>
__device__ __forceinline__ void gemm128(unsigned short* __restrict__ ldsbuf,
                                        const unsigned short* __restrict__ A,
                                        const unsigned short* __restrict__ Bt,
                                        void* __restrict__ Cout,
                                        int m0, int n0, int K, int ldc) {
  unsigned short* As = ldsbuf;             // 128*32 shorts
  unsigned short* Bs = ldsbuf + 4096;      // 128*32 shorts
  const int tid = threadIdx.x;
  const int wave = tid >> 6, lane = tid & 63;
  const int ln = lane & 15, g = lane >> 4;
  const int wm = (wave >> 1) * 64, wn = (wave & 1) * 64;

  const int rA0 = wave * 16 + (lane >> 2);
  const int rA1 = 64 + wave * 16 + (lane >> 2);
  const int colx = (lane & 3) * 8;
  const unsigned short* gA0 = A + (size_t)(m0 + rA0) * K + colx;
  const unsigned short* gA1 = A + (size_t)(m0 + rA1) * K + colx;
  const unsigned short* gB0 = Bt + (size_t)(n0 + rA0) * K + colx;
  const unsigned short* gB1 = Bt + (size_t)(n0 + rA1) * K + colx;
  unsigned short* lA0 = As + wave * 512;
  unsigned short* lA1 = As + 2048 + wave * 512;
  unsigned short* lB0 = Bs + wave * 512;
  unsigned short* lB1 = Bs + 2048 + wave * 512;

  f32x4 acc[4][4] = {};

  for (int k0 = 0; k0 < K; k0 += 32) {
    gload16(gA0 + k0, lA0);
    gload16(gA1 + k0, lA1);
    gload16(gB0 + k0, lB0);
    gload16(gB1 + k0, lB1);
    __syncthreads();
    short8_t a[4], b[4];
#pragma unroll
    for (int i = 0; i < 4; ++i)
      a[i] = *(const short8_t*)(As + (wm + i * 16 + ln) * 32 + g * 8);
#pragma unroll
    for (int j = 0; j < 4; ++j)
      b[j] = *(const short8_t*)(Bs + (wn + j * 16 + ln) * 32 + g * 8);
#pragma unroll
    for (int i = 0; i < 4; ++i)
#pragma unroll
      for (int j = 0; j < 4; ++j)
        acc[i][j] = mfma16(a[i], b[j], acc[i][j]);
    __syncthreads();
  }

#pragma unroll
  for (int i = 0; i < 4; ++i) {
#pragma unroll
    for (int j = 0; j < 4; ++j) {
      if (MODE == 2) {
        int row0 = m0 + wm + i * 16 + g * 4;
        int col = n0 + wn + j * 16 + ln;
        us4_t pk;
#pragma unroll
        for (int r = 0; r < 4; ++r) pk[r] = f2b(acc[i][j][r]);
        *(us4_t*)((unsigned short*)Cout +
                  ((size_t)((row0 >> 11) * 1024 + col)) * 2048 + (row0 & 2047)) = pk;
      } else {
#pragma unroll
        for (int r = 0; r < 4; ++r) {
          int row = m0 + wm + i * 16 + g * 4 + r;
          int col = n0 + wn + j * 16 + ln;
          ((unsigned short*)Cout)[(size_t)row * ldc + col] = f2b(acc[i][j][r]);
        }
      }
    }
  }
}

// Q projection: grid (16,16), 256 tiles exactly = 1 full round of 256 CUs.
__global__ __launch_bounds__(512, 1) void gemm_q_kernel(
    const unsigned short* __restrict__ xb, const unsigned short* __restrict__ wqb,
    unsigned short* __restrict__ xq) {
  __shared__ __align__(16) unsigned short lds[65536];
  gemm256_core<1>(lds, xb, wqb, xq, blockIdx.y * 256, blockIdx.x * 256, 4096, 4096);
}

// K/V projections: grid (16, 32), 128^2 tiles, high occupancy (16 KB LDS).
__global__ __launch_bounds__(256) void gemm_kv_kernel(
    const unsigned short* __restrict__ xb, const unsigned short* __restrict__ wkb,
    const unsigned short* __restrict__ wvb, unsigned short* __restrict__ xk,
    unsigned short* __restrict__ xvT) {
  __shared__ __align__(16) unsigned short lds[8192];  // 16 KiB
  int bx = blockIdx.x, by = blockIdx.y;
  if (bx < 8) gemm128<1>(lds, xb, wkb, xk, by * 128, bx * 128, 4096, 1024);
  else        gemm128<2>(lds, xb, wvb, xvT, by * 128, (bx - 8) * 128, 4096, 0);
}

__global__ __launch_bounds__(512, 1) void gemm_o_kernel(
    const unsigned short* __restrict__ ao, const unsigned short* __restrict__ wob,
    float* __restrict__ out) {
  __shared__ __align__(16) unsigned short lds[65536];
  gemm256_core<0>(lds, ao, wob, out, blockIdx.y * 256, blockIdx.x * 256, 4096, 4096);
}

// ---------------- RoPE ----------------
template <int NH>
__global__ void rope_kernel(unsigned short* __restrict__ p, const float* __restrict__ fr,
                            int nchunks) {
  for (int c = blockIdx.x * blockDim.x + threadIdx.x; c < nchunks;
       c += gridDim.x * blockDim.x) {
    size_t e = (size_t)c * 8;
    int f0 = (c & 15) * 4;
    int rest = (int)(e >> 7);
    int s = (rest / NH) & 2047;
    unsigned short* ptr = p + e;
    short8_t v = *(short8_t*)ptr;
    const float* cosp = fr + (size_t)s * 64 + f0;
    const float* sinp = cosp + 131072;
#pragma unroll
    for (int j = 0; j < 4; ++j) {
      float re = b2f((unsigned short)v[2 * j]);
      float im = b2f((unsigned short)v[2 * j + 1]);
      float cc = cosp[j], ss = sinp[j];
      v[2 * j]     = (short)f2b(re * cc - im * ss);
      v[2 * j + 1] = (short)f2b(re * ss + im * cc);
    }
    *(short8_t*)ptr = v;
  }
}

// ---------------- flash attention: 8 waves x 32 q-rows, 32x32 MFMA, swapped QK ----------------
// CU pairing balance: ord and ord+256 differ only in z (batch); complementary
// bx mapping makes each CU's two blocks sum to 36 tile-units (was 2x same).
__global__ __launch_bounds__(512, 2) void attn_kernel(
    const unsigned short* __restrict__ xq, const unsigned short* __restrict__ xk,
    const unsigned short* __restrict__ xvT, unsigned short* __restrict__ ao) {
  __shared__ __align__(16) unsigned char smem[56320];
  const int tid = threadIdx.x;
  const int wq = tid >> 6, lane = tid & 63;
  const int q31 = lane & 31, hi = lane >> 5;
  const int bx = blockIdx.z ? (int)blockIdx.x : 7 - (int)blockIdx.x;
  const int h = blockIdx.y, b = blockIdx.z;
  const int hkv = h >> 2;
  const int q0 = bx * 256;
  const int a0 = q0 + wq * 32;
  const int ktmax_w = a0 >> 6;
  const int NT = bx * 4 + 4;

  const unsigned short* kbase = xk + ((size_t)(b * 2048) * 8 + hkv) * 128;
  const unsigned short* vtg = xvT + (size_t)(b * 1024 + hkv * 128) * 2048;

  const unsigned short* qrow = xq + ((size_t)(b * 2048 + a0 + q31) * 32 + h) * 128;
  short8_t qf[8];
#pragma unroll
  for (int st = 0; st < 8; ++st) qf[st] = *(const short8_t*)(qrow + st * 16 + hi * 8);

  const int c0 = tid, c1 = tid + 512;
  const int kg0 = (c0 >> 4) * 1024 + (c0 & 15) * 8;
  const int kg1 = (c1 >> 4) * 1024 + (c1 & 15) * 8;
  const int ka0 = (c0 >> 4) * 256 + (((c0 & 15) ^ ((c0 >> 4) & 7)) << 4);
  const int ka1 = (c1 >> 4) * 256 + (((c1 & 15) ^ ((c1 >> 4) & 7)) << 4);
  const int d0 = tid >> 3, kb0 = tid & 7, d1v = d0 + 64;
  const int vg0 = d0 * 2048 + kb0 * 8, vg1 = d1v * 2048 + kb0 * 8;
  const int va0 = d0 * 72 + kb0 * 8, va1 = d1v * 72 + kb0 * 8;

  unsigned short* Kb = (unsigned short*)(smem);
  unsigned short* VT = (unsigned short*)(smem + 16384);
  unsigned short* pp = (unsigned short*)(smem + 34816) + wq * 1280;
  unsigned short* prow = pp + q31 * 40;
  float* cl = (float*)(smem + 55296) + wq * 32;

  f32x16 o[4] = {};
  float m_run = -1e30f, l_run = 0.f;

  short8_t kr0 = *(const short8_t*)(kbase + kg0);
  short8_t kr1 = *(const short8_t*)(kbase + kg1);
  short8_t vr0 = *(const short8_t*)(vtg + vg0);
  short8_t vr1 = *(const short8_t*)(vtg + vg1);

  for (int kt = 0; kt < NT; ++kt) {
    *(short8_t*)((unsigned char*)Kb + ka0) = kr0;
    *(short8_t*)((unsigned char*)Kb + ka1) = kr1;
    *(short8_t*)(VT + va0) = vr0;
    *(short8_t*)(VT + va1) = vr1;
    __syncthreads();
    if (kt + 1 < NT) {
      const unsigned short* kg = kbase + (size_t)(kt + 1) * 65536;
      kr0 = *(const short8_t*)(kg + kg0);
      kr1 = *(const short8_t*)(kg + kg1);
      vr0 = *(const short8_t*)(vtg + vg0 + (kt + 1) * 64);
      vr1 = *(const short8_t*)(vtg + vg1 + (kt + 1) * 64);
    }

    if (kt <= ktmax_w) {
      const int r7 = (q31 & 7) << 4;
      f32x16 p0 = {}, p1 = {};
      __builtin_amdgcn_s_setprio(1);
#pragma unroll
      for (int st = 0; st < 8; ++st) {
        int cb = (((st * 2 + hi) << 4)) ^ r7;
        short8_t k0 = *(const short8_t*)((const unsigned char*)Kb + q31 * 256 + cb);
        short8_t k1 = *(const short8_t*)((const unsigned char*)Kb + (q31 + 32) * 256 + cb);
        p0 = mfma32(k0, qf[st], p0);
        p1 = mfma32(k1, qf[st], p1);
      }
      __builtin_amdgcn_s_setprio(0);

      if (kt == ktmax_w) {
        const int q = a0 + q31;
#pragma unroll
        for (int r = 0; r < 16; ++r) {
          int crow = (r & 3) + 8 * (r >> 2) + 4 * hi;
          int kgl = kt * 64 + crow;
          if (kgl > q) p0[r] = -1e30f;
          if (kgl + 32 > q) p1[r] = -1e30f;
        }
      }
      float mx = -1e30f;
#pragma unroll
      for (int r = 0; r < 16; ++r) mx = fmaxf(mx, fmaxf(p0[r], p1[r]));
      mx = fmaxf(mx, __shfl_xor(mx, 32));
      float mnew = fmaxf(m_run, mx);
      float corr = exp2f((m_run - mnew) * CEXP);
      m_run = mnew;
      float sum = 0.f;
#pragma unroll
      for (int r = 0; r < 16; ++r) {
        p0[r] = exp2f((p0[r] - mnew) * CEXP);
        p1[r] = exp2f((p1[r] - mnew) * CEXP);
        sum += p0[r] + p1[r];
      }
      sum += __shfl_xor(sum, 32);
      l_run = l_run * corr + sum;

      cl[q31] = corr;
      f32x4 cv0 = *(const f32x4*)(cl + hi * 4);
      f32x4 cv1 = *(const f32x4*)(cl + 8 + hi * 4);
      f32x4 cv2 = *(const f32x4*)(cl + 16 + hi * 4);
      f32x4 cv3 = *(const f32x4*)(cl + 24 + hi * 4);
#pragma unroll
      for (int db = 0; db < 4; ++db) {
#pragma unroll
        for (int r = 0; r < 4; ++r) {
          o[db][r]      *= cv0[r];
          o[db][4 + r]  *= cv1[r];
          o[db][8 + r]  *= cv2[r];
          o[db][12 + r] *= cv3[r];
        }
      }

#pragma unroll
      for (int u = 0; u < 4; ++u) {
        int2v w;
        w[0] = (int)((unsigned)f2b(p0[4 * u]) | ((unsigned)f2b(p0[4 * u + 1]) << 16));
        w[1] = (int)((unsigned)f2b(p0[4 * u + 2]) | ((unsigned)f2b(p0[4 * u + 3]) << 16));
        *(int2v*)(prow + u * 8 + hi * 4) = w;
      }
      {
        short8_t pa0 = *(const short8_t*)(prow + hi * 8);
        short8_t pa1 = *(const short8_t*)(prow + 16 + hi * 8);
        __builtin_amdgcn_s_setprio(1);
#pragma unroll
        for (int db = 0; db < 4; ++db) {
          const unsigned short* vtd = VT + (db * 32 + q31) * 72;
          short8_t vf0 = *(const short8_t*)(vtd + hi * 8);
          short8_t vf1 = *(const short8_t*)(vtd + 16 + hi * 8);
          o[db] = mfma32(pa0, vf0, o[db]);
          o[db] = mfma32(pa1, vf1, o[db]);
        }
        __builtin_amdgcn_s_setprio(0);
      }
#pragma unroll
      for (int u = 0; u < 4; ++u) {
        int2v w;
        w[0] = (int)((unsigned)f2b(p1[4 * u]) | ((unsigned)f2b(p1[4 * u + 1]) << 16));
        w[1] = (int)((unsigned)f2b(p1[4 * u + 2]) | ((unsigned)f2b(p1[4 * u + 3]) << 16));
        *(int2v*)(prow + u * 8 + hi * 4) = w;
      }
      {
        short8_t pa2 = *(const short8_t*)(prow + hi * 8);
        short8_t pa3 = *(const short8_t*)(prow + 16 + hi * 8);
        __builtin_amdgcn_s_setprio(1);
#pragma unroll
        for (int db = 0; db < 4; ++db) {
          const unsigned short* vtd = VT + (db * 32 + q31) * 72;
          short8_t vf2 = *(const short8_t*)(vtd + 32 + hi * 8);
          short8_t vf3 = *(const short8_t*)(vtd + 48 + hi * 8);
          o[db] = mfma32(pa2, vf2, o[db]);
          o[db] = mfma32(pa3, vf3, o[db]);
        }
        __builtin_amdgcn_s_setprio(0);
      }
    }
    __syncthreads();
  }

  cl[q31] = l_run;
  f32x4 lv0 = *(const f32x4*)(cl + hi * 4);
  f32x4 lv1 = *(const f32x4*)(cl + 8 + hi * 4);
  f32x4 lv2 = *(const f32x4*)(cl + 16 + hi * 4);
  f32x4 lv3 = *(const f32x4*)(cl + 24 + hi * 4);
  f32x4 iv0, iv1, iv2, iv3;
#pragma unroll
  for (int r = 0; r < 4; ++r) {
    iv0[r] = 1.0f / lv0[r]; iv1[r] = 1.0f / lv1[r];
    iv2[r] = 1.0f / lv2[r]; iv3[r] = 1.0f / lv3[r];
  }
  unsigned short* ob = ao + ((size_t)(b * 2048 + a0) * 32 + h) * 128;
#pragma unroll
  for (int db = 0; db < 4; ++db) {
#pragma unroll
    for (int r = 0; r < 16; ++r) {
      int crow = (r & 3) + 8 * (r >> 2) + 4 * hi;
      float iv = (r < 4) ? iv0[r & 3] : (r < 8) ? iv1[r & 3] : (r < 12) ? iv2[r & 3] : iv3[r & 3];
      ob[(size_t)crow * 4096 + db * 32 + q31] = f2b(o[db][r] * iv);
    }
  }
}

// ---------------- launch ----------------
extern "C" void kernel_launch(void* const* d_in, const int* in_sizes, int n_in,
                              void* d_out, int out_size, void* d_ws, size_t ws_size,
                              hipStream_t stream) {
  const float* x  = (const float*)d_in[0];
  const float* wq = (const float*)d_in[1];
  const float* wk = (const float*)d_in[2];
  const float* wv = (const float*)d_in[3];
  const float* wo = (const float*)d_in[4];
  const float* fr = (const float*)d_in[7];
  float* out = (float*)d_out;

  char* ws = (char*)d_ws;
  unsigned short* xb  = (unsigned short*)(ws);               // 33.5MB; reused as ao
  unsigned short* wqb = (unsigned short*)(ws + 33554432);    // 33.5MB; reused as wob
  unsigned short* wkb = (unsigned short*)(ws + 67108864);    // 8.4MB
  unsigned short* wvb = (unsigned short*)(ws + 75497472);    // 8.4MB
  unsigned short* xq  = (unsigned short*)(ws + 83886080);    // 33.5MB
  unsigned short* xk  = (unsigned short*)(ws + 117440512);   // 8.4MB
  unsigned short* xvT = (unsigned short*)(ws + 125829120);   // 8.4MB (total 128MiB)
  unsigned short* ao  = xb;
  unsigned short* wob = wqb;

  dim3 blk(256);
  cvt_kernel<<<dim3(1024), blk, 0, stream>>>(x,  xb,  16777216 / 4);
  cvt_kernel<<<dim3(1024), blk, 0, stream>>>(wq, wqb, 16777216 / 4);
  cvt_kernel<<<dim3(512),  blk, 0, stream>>>(wk, wkb, 4194304 / 4);
  cvt_kernel<<<dim3(512),  blk, 0, stream>>>(wv, wvb, 4194304 / 4);

  gemm_q_kernel<<<dim3(16, 16), dim3(512), 0, stream>>>(xb, wqb, xq);
  gemm_kv_kernel<<<dim3(16, 32), dim3(256), 0, stream>>>(xb, wkb, wvb, xk, xvT);

  rope_kernel<32><<<dim3(2048), blk, 0, stream>>>(xq, fr, 2097152);
  rope_kernel<8><<<dim3(512),  blk, 0, stream>>>(xk, fr, 524288);

  cvt_kernel<<<dim3(1024), blk, 0, stream>>>(wo, wob, 16777216 / 4);

  attn_kernel<<<dim3(8, 32, 2), dim3(512), 0, stream>>>(xq, xk, xvT, ao);

  gemm_o_kernel<<<dim3(16, 16), dim3(512), 0, stream>>>(ao, wob, out);
}

// Round 17
// 531.164 us; speedup vs baseline: 1.2853x; 1.0233x over previous
//
#include <hip/hip_runtime.h>

typedef __bf16 bf16x8 __attribute__((ext_vector_type(8)));
typedef short short8_t __attribute__((ext_vector_type(8)));
typedef float f32x4 __attribute__((ext_vector_type(4)));
typedef float f32x16 __attribute__((ext_vector_type(16)));
typedef int int2v __attribute__((ext_vector_type(2)));
typedef unsigned short us4_t __attribute__((ext_vector_type(4)));

#define SCALE 0.08838834764831845f  // 1/sqrt(128)
#define CEXP 0.1275179f             // SCALE * log2(e)

#define VMCNT(n) asm volatile("s_waitcnt vmcnt(" #n ")" ::: "memory")

__device__ __forceinline__ float b2f(unsigned short u) {
  union { unsigned int i; float f; } v; v.i = ((unsigned int)u) << 16; return v.f;
}
__device__ __forceinline__ unsigned short f2b(float f) {
  union { float f; unsigned int i; } v; v.f = f;
  unsigned int r = v.i + 0x7fffu + ((v.i >> 16) & 1u);
  return (unsigned short)(r >> 16);
}
// truncating pack: low short = bf16(lo) (trunc), high short = bf16(hi) (trunc)
__device__ __forceinline__ int packtr(float lo, float hi_) {
  unsigned a = __builtin_bit_cast(unsigned, lo) >> 16;
  unsigned b = __builtin_bit_cast(unsigned, hi_) & 0xffff0000u;
  return (int)(a | b);
}

__device__ __forceinline__ f32x4 mfma16(short8_t a, short8_t b, f32x4 c) {
  return __builtin_amdgcn_mfma_f32_16x16x32_bf16(
      __builtin_bit_cast(bf16x8, a), __builtin_bit_cast(bf16x8, b), c, 0, 0, 0);
}
__device__ __forceinline__ f32x16 mfma32(short8_t a, short8_t b, f32x16 c) {
  return __builtin_amdgcn_mfma_f32_32x32x16_bf16(
      __builtin_bit_cast(bf16x8, a), __builtin_bit_cast(bf16x8, b), c, 0, 0, 0);
}

typedef __attribute__((address_space(1))) const void gas_t;
typedef __attribute__((address_space(3))) void las_t;
__device__ __forceinline__ void gload16(const void* g, void* l) {
  __builtin_amdgcn_global_load_lds((gas_t*)g, (las_t*)l, 16, 0, 0);
}

// ---------------- fp32 -> bf16 convert ----------------
__global__ void cvt_kernel(const float* __restrict__ src, unsigned short* __restrict__ dst, int n4) {
  for (int i = blockIdx.x * blockDim.x + threadIdx.x; i < n4; i += gridDim.x * blockDim.x) {
    f32x4 v = *(const f32x4*)(src + (size_t)i * 4);
    us4_t o;
    o[0] = f2b(v[0]); o[1] = f2b(v[1]); o[2] = f2b(v[2]); o[3] = f2b(v[3]);
    *(us4_t*)(dst + (size_t)i * 4) = o;
  }
}

// ============ 256x256 counted-vmcnt pipelined GEMM core (R12, verified) ============
// MODE: 0 = f32 out, 1 = bf16 out
template <int MODE>
__device__ __forceinline__ void gemm256_core(
    unsigned short* __restrict__ lds,
    const unsigned short* __restrict__ A, const unsigned short* __restrict__ Bt,
    void* __restrict__ Cout, int m0, int n0, int K, int ldc) {
  const int tid = threadIdx.x;
  const int wid = tid >> 6, lane = tid & 63;
  const int ln = lane & 15, lg = lane >> 4;
  const int wm = wid >> 2, wn = wid & 3;
  const int NT = K >> 5;

  const int sr0 = wid * 16 + (lane >> 2);
  const int sr1 = 128 + sr0;
  const int sj0 = ((lane & 3) ^ ((sr0 >> 1) & 3)) * 8;
  const int sj1 = ((lane & 3) ^ ((sr1 >> 1) & 3)) * 8;
  const unsigned short* gA0 = A + (size_t)(m0 + sr0) * K + sj0;
  const unsigned short* gA1 = A + (size_t)(m0 + sr1) * K + sj1;
  const unsigned short* gB0 = Bt + (size_t)(n0 + sr0) * K + sj0;
  const unsigned short* gB1 = Bt + (size_t)(n0 + sr1) * K + sj1;
  unsigned short* dA = lds + wid * 512;
  unsigned short* dB = lds + 32768 + wid * 512;

  const int swz = (ln >> 1) & 3;
  const int jA = (lg ^ swz) << 4;
  const unsigned char* ldsb = (const unsigned char*)lds;
  const int aoff = (wm * 128 + ln) * 64 + jA;
  const int boff = 65536 + (wn * 64 + ln) * 64 + jA;

  f32x4 acc[8][4] = {};

#define STAGE_A(t_) { int s_ = (t_) & 3; int k0_ = (t_) << 5; \
    gload16(gA0 + k0_, dA + s_ * 8192); \
    gload16(gA1 + k0_, dA + s_ * 8192 + 4096); }
#define STAGE_B(t_) { int s_ = (t_) & 3; int k0_ = (t_) << 5; \
    gload16(gB0 + k0_, dB + s_ * 8192); \
    gload16(gB1 + k0_, dB + s_ * 8192 + 4096); }

  STAGE_A(0); STAGE_B(0);
  STAGE_A(1); STAGE_B(1);
  STAGE_A(2); STAGE_B(2);
  VMCNT(8);
  __builtin_amdgcn_s_barrier();

  for (int t = 0; t < NT; ++t) {
    const int sb = (t & 3) * 16384;
    if (t + 3 < NT) { STAGE_A(t + 3); STAGE_B(t + 3); }
    short8_t af[8], bf[4];
#pragma unroll
    for (int mi = 0; mi < 8; ++mi)
      af[mi] = *(const short8_t*)(ldsb + sb + aoff + mi * 1024);
#pragma unroll
    for (int nj = 0; nj < 4; ++nj)
      bf[nj] = *(const short8_t*)(ldsb + sb + boff + nj * 1024);
    if (t < NT - 3) { VMCNT(8); }
    else if (t == NT - 3) { VMCNT(4); }
    else if (t == NT - 2) { VMCNT(0); }
    __builtin_amdgcn_s_barrier();
    asm volatile("s_waitcnt lgkmcnt(0)" ::: "memory");
    __builtin_amdgcn_sched_barrier(0);
    __builtin_amdgcn_s_setprio(1);
#pragma unroll
    for (int mi = 0; mi < 8; ++mi)
#pragma unroll
      for (int nj = 0; nj < 4; ++nj)
        acc[mi][nj] = mfma16(af[mi], bf[nj], acc[mi][nj]);
    __builtin_amdgcn_s_setprio(0);
    __builtin_amdgcn_s_barrier();
  }
#undef STAGE_A
#undef STAGE_B

#pragma unroll
  for (int mi = 0; mi < 8; ++mi) {
#pragma unroll
    for (int nj = 0; nj < 4; ++nj) {
#pragma unroll
      for (int r = 0; r < 4; ++r) {
        int row = m0 + wm * 128 + mi * 16 + lg * 4 + r;
        int col = n0 + wn * 64 + nj * 16 + ln;
        if (MODE == 1)
          ((unsigned short*)Cout)[(size_t)row * ldc + col] = f2b(acc[mi][nj][r]);
        else
          ((float*)Cout)[(size_t)row * ldc + col] = acc[mi][nj][r];
      }
    }
  }
}

// ============ 128x128 GEMM core (R6, verified) — for K/V projections ============
// MODE: 1 = bf16 out, 2 = bf16 transposed-V out
template <int MODE>
__device__ __forceinline__ void gemm128(unsigned short* __restrict__ ldsbuf,
                                        const unsigned short* __restrict__ A,
                                        const unsigned short* __restrict__ Bt,
                                        void* __restrict__ Cout,
                                        int m0, int n0, int K, int ldc) {
  unsigned short* As = ldsbuf;
  unsigned short* Bs = ldsbuf + 4096;
  const int tid = threadIdx.x;
  const int wave = tid >> 6, lane = tid & 63;
  const int ln = lane & 15, g = lane >> 4;
  const int wm = (wave >> 1) * 64, wn = (wave & 1) * 64;

  const int rA0 = wave * 16 + (lane >> 2);
  const int rA1 = 64 + wave * 16 + (lane >> 2);
  const int colx = (lane & 3) * 8;
  const unsigned short* gA0 = A + (size_t)(m0 + rA0) * K + colx;
  const unsigned short* gA1 = A + (size_t)(m0 + rA1) * K + colx;
  const unsigned short* gB0 = Bt + (size_t)(n0 + rA0) * K + colx;
  const unsigned short* gB1 = Bt + (size_t)(n0 + rA1) * K + colx;
  unsigned short* lA0 = As + wave * 512;
  unsigned short* lA1 = As + 2048 + wave * 512;
  unsigned short* lB0 = Bs + wave * 512;
  unsigned short* lB1 = Bs + 2048 + wave * 512;

  f32x4 acc[4][4] = {};

  for (int k0 = 0; k0 < K; k0 += 32) {
    gload16(gA0 + k0, lA0);
    gload16(gA1 + k0, lA1);
    gload16(gB0 + k0, lB0);
    gload16(gB1 + k0, lB1);
    __syncthreads();
    short8_t a[4], b[4];
#pragma unroll
    for (int i = 0; i < 4; ++i)
      a[i] = *(const short8_t*)(As + (wm + i * 16 + ln) * 32 + g * 8);
#pragma unroll
    for (int j = 0; j < 4; ++j)
      b[j] = *(const short8_t*)(Bs + (wn + j * 16 + ln) * 32 + g * 8);
#pragma unroll
    for (int i = 0; i < 4; ++i)
#pragma unroll
      for (int j = 0; j < 4; ++j)
        acc[i][j] = mfma16(a[i], b[j], acc[i][j]);
    __syncthreads();
  }

#pragma unroll
  for (int i = 0; i < 4; ++i) {
#pragma unroll
    for (int j = 0; j < 4; ++j) {
      if (MODE == 2) {
        int row0 = m0 + wm + i * 16 + g * 4;
        int col = n0 + wn + j * 16 + ln;
        us4_t pk;
#pragma unroll
        for (int r = 0; r < 4; ++r) pk[r] = f2b(acc[i][j][r]);
        *(us4_t*)((unsigned short*)Cout +
                  ((size_t)((row0 >> 11) * 1024 + col)) * 2048 + (row0 & 2047)) = pk;
      } else {
#pragma unroll
        for (int r = 0; r < 4; ++r) {
          int row = m0 + wm + i * 16 + g * 4 + r;
          int col = n0 + wn + j * 16 + ln;
          ((unsigned short*)Cout)[(size_t)row * ldc + col] = f2b(acc[i][j][r]);
        }
      }
    }
  }
}

// Q projection: grid (16,16), 256 tiles exactly = 1 full round of 256 CUs.
__global__ __launch_bounds__(512, 1) void gemm_q_kernel(
    const unsigned short* __restrict__ xb, const unsigned short* __restrict__ wqb,
    unsigned short* __restrict__ xq) {
  __shared__ __align__(16) unsigned short lds[65536];
  gemm256_core<1>(lds, xb, wqb, xq, blockIdx.y * 256, blockIdx.x * 256, 4096, 4096);
}

// K/V projections: grid (16, 32), 128^2 tiles, high occupancy (16 KB LDS).
__global__ __launch_bounds__(256) void gemm_kv_kernel(
    const unsigned short* __restrict__ xb, const unsigned short* __restrict__ wkb,
    const unsigned short* __restrict__ wvb, unsigned short* __restrict__ xk,
    unsigned short* __restrict__ xvT) {
  __shared__ __align__(16) unsigned short lds[8192];
  int bx = blockIdx.x, by = blockIdx.y;
  if (bx < 8) gemm128<1>(lds, xb, wkb, xk, by * 128, bx * 128, 4096, 1024);
  else        gemm128<2>(lds, xb, wvb, xvT, by * 128, (bx - 8) * 128, 4096, 0);
}

__global__ __launch_bounds__(512, 1) void gemm_o_kernel(
    const unsigned short* __restrict__ ao, const unsigned short* __restrict__ wob,
    float* __restrict__ out) {
  __shared__ __align__(16) unsigned short lds[65536];
  gemm256_core<0>(lds, ao, wob, out, blockIdx.y * 256, blockIdx.x * 256, 4096, 4096);
}

// ---------------- RoPE ----------------
template <int NH>
__global__ void rope_kernel(unsigned short* __restrict__ p, const float* __restrict__ fr,
                            int nchunks) {
  for (int c = blockIdx.x * blockDim.x + threadIdx.x; c < nchunks;
       c += gridDim.x * blockDim.x) {
    size_t e = (size_t)c * 8;
    int f0 = (c & 15) * 4;
    int rest = (int)(e >> 7);
    int s = (rest / NH) & 2047;
    unsigned short* ptr = p + e;
    short8_t v = *(short8_t*)ptr;
    const float* cosp = fr + (size_t)s * 64 + f0;
    const float* sinp = cosp + 131072;
#pragma unroll
    for (int j = 0; j < 4; ++j) {
      float re = b2f((unsigned short)v[2 * j]);
      float im = b2f((unsigned short)v[2 * j + 1]);
      float cc = cosp[j], ss = sinp[j];
      v[2 * j]     = (short)f2b(re * cc - im * ss);
      v[2 * j + 1] = (short)f2b(re * ss + im * cc);
    }
    *(short8_t*)ptr = v;
  }
}

// ---------------- flash attention: 8 waves x 32 q-rows, 32x32 MFMA, swapped QK ----------------
// R16 CU-pairing balance + R17: truncating P-pack, defer-max (THR=30 S-units).
__global__ __launch_bounds__(512, 2) void attn_kernel(
    const unsigned short* __restrict__ xq, const unsigned short* __restrict__ xk,
    const unsigned short* __restrict__ xvT, unsigned short* __restrict__ ao) {
  __shared__ __align__(16) unsigned char smem[56320];
  const int tid = threadIdx.x;
  const int wq = tid >> 6, lane = tid & 63;
  const int q31 = lane & 31, hi = lane >> 5;
  const int bx = blockIdx.z ? (int)blockIdx.x : 7 - (int)blockIdx.x;
  const int h = blockIdx.y, b = blockIdx.z;
  const int hkv = h >> 2;
  const int q0 = bx * 256;
  const int a0 = q0 + wq * 32;
  const int ktmax_w = a0 >> 6;
  const int NT = bx * 4 + 4;

  const unsigned short* kbase = xk + ((size_t)(b * 2048) * 8 + hkv) * 128;
  const unsigned short* vtg = xvT + (size_t)(b * 1024 + hkv * 128) * 2048;

  const unsigned short* qrow = xq + ((size_t)(b * 2048 + a0 + q31) * 32 + h) * 128;
  short8_t qf[8];
#pragma unroll
  for (int st = 0; st < 8; ++st) qf[st] = *(const short8_t*)(qrow + st * 16 + hi * 8);

  const int c0 = tid, c1 = tid + 512;
  const int kg0 = (c0 >> 4) * 1024 + (c0 & 15) * 8;
  const int kg1 = (c1 >> 4) * 1024 + (c1 & 15) * 8;
  const int ka0 = (c0 >> 4) * 256 + (((c0 & 15) ^ ((c0 >> 4) & 7)) << 4);
  const int ka1 = (c1 >> 4) * 256 + (((c1 & 15) ^ ((c1 >> 4) & 7)) << 4);
  const int d0 = tid >> 3, kb0 = tid & 7, d1v = d0 + 64;
  const int vg0 = d0 * 2048 + kb0 * 8, vg1 = d1v * 2048 + kb0 * 8;
  const int va0 = d0 * 72 + kb0 * 8, va1 = d1v * 72 + kb0 * 8;

  unsigned short* Kb = (unsigned short*)(smem);
  unsigned short* VT = (unsigned short*)(smem + 16384);
  unsigned short* pp = (unsigned short*)(smem + 34816) + wq * 1280;
  unsigned short* prow = pp + q31 * 40;
  float* cl = (float*)(smem + 55296) + wq * 32;

  f32x16 o[4] = {};
  float m_run = -1e30f, l_run = 0.f;

  short8_t kr0 = *(const short8_t*)(kbase + kg0);
  short8_t kr1 = *(const short8_t*)(kbase + kg1);
  short8_t vr0 = *(const short8_t*)(vtg + vg0);
  short8_t vr1 = *(const short8_t*)(vtg + vg1);

  for (int kt = 0; kt < NT; ++kt) {
    *(short8_t*)((unsigned char*)Kb + ka0) = kr0;
    *(short8_t*)((unsigned char*)Kb + ka1) = kr1;
    *(short8_t*)(VT + va0) = vr0;
    *(short8_t*)(VT + va1) = vr1;
    __syncthreads();
    if (kt + 1 < NT) {
      const unsigned short* kg = kbase + (size_t)(kt + 1) * 65536;
      kr0 = *(const short8_t*)(kg + kg0);
      kr1 = *(const short8_t*)(kg + kg1);
      vr0 = *(const short8_t*)(vtg + vg0 + (kt + 1) * 64);
      vr1 = *(const short8_t*)(vtg + vg1 + (kt + 1) * 64);
    }

    if (kt <= ktmax_w) {
      const int r7 = (q31 & 7) << 4;
      f32x16 p0 = {}, p1 = {};
      __builtin_amdgcn_s_setprio(1);
#pragma unroll
      for (int st = 0; st < 8; ++st) {
        int cb = (((st * 2 + hi) << 4)) ^ r7;
        short8_t k0 = *(const short8_t*)((const unsigned char*)Kb + q31 * 256 + cb);
        short8_t k1 = *(const short8_t*)((const unsigned char*)Kb + (q31 + 32) * 256 + cb);
        p0 = mfma32(k0, qf[st], p0);
        p1 = mfma32(k1, qf[st], p1);
      }
      __builtin_amdgcn_s_setprio(0);

      if (kt == ktmax_w) {
        const int q = a0 + q31;
#pragma unroll
        for (int r = 0; r < 16; ++r) {
          int crow = (r & 3) + 8 * (r >> 2) + 4 * hi;
          int kgl = kt * 64 + crow;
          if (kgl > q) p0[r] = -1e30f;
          if (kgl + 32 > q) p1[r] = -1e30f;
        }
      }
      // ---- online softmax with defer-max (T13) ----
      float mx = -1e30f;
#pragma unroll
      for (int r = 0; r < 16; ++r) mx = fmaxf(mx, fmaxf(p0[r], p1[r]));
      mx = fmaxf(mx, __shfl_xor(mx, 32));
      const bool defer = __all(mx <= m_run + 30.0f);   // P bounded by 2^(30*CEXP)~14
      const float mnew = defer ? m_run : fmaxf(m_run, mx);
      float sum = 0.f;
#pragma unroll
      for (int r = 0; r < 16; ++r) {
        p0[r] = exp2f((p0[r] - mnew) * CEXP);
        p1[r] = exp2f((p1[r] - mnew) * CEXP);
        sum += p0[r] + p1[r];
      }
      sum += __shfl_xor(sum, 32);
      if (defer) {
        l_run += sum;
      } else {
        float corr = exp2f((m_run - mnew) * CEXP);
        m_run = mnew;
        l_run = l_run * corr + sum;
        cl[q31] = corr;
        f32x4 cv0 = *(const f32x4*)(cl + hi * 4);
        f32x4 cv1 = *(const f32x4*)(cl + 8 + hi * 4);
        f32x4 cv2 = *(const f32x4*)(cl + 16 + hi * 4);
        f32x4 cv3 = *(const f32x4*)(cl + 24 + hi * 4);
#pragma unroll
        for (int db = 0; db < 4; ++db) {
#pragma unroll
          for (int r = 0; r < 4; ++r) {
            o[db][r]      *= cv0[r];
            o[db][4 + r]  *= cv1[r];
            o[db][8 + r]  *= cv2[r];
            o[db][12 + r] *= cv3[r];
          }
        }
      }

#pragma unroll
      for (int u = 0; u < 4; ++u) {
        int2v w;
        w[0] = packtr(p0[4 * u], p0[4 * u + 1]);
        w[1] = packtr(p0[4 * u + 2], p0[4 * u + 3]);
        *(int2v*)(prow + u * 8 + hi * 4) = w;
      }
      {
        short8_t pa0 = *(const short8_t*)(prow + hi * 8);
        short8_t pa1 = *(const short8_t*)(prow + 16 + hi * 8);
        __builtin_amdgcn_s_setprio(1);
#pragma unroll
        for (int db = 0; db < 4; ++db) {
          const unsigned short* vtd = VT + (db * 32 + q31) * 72;
          short8_t vf0 = *(const short8_t*)(vtd + hi * 8);
          short8_t vf1 = *(const short8_t*)(vtd + 16 + hi * 8);
          o[db] = mfma32(pa0, vf0, o[db]);
          o[db] = mfma32(pa1, vf1, o[db]);
        }
        __builtin_amdgcn_s_setprio(0);
      }
#pragma unroll
      for (int u = 0; u < 4; ++u) {
        int2v w;
        w[0] = packtr(p1[4 * u], p1[4 * u + 1]);
        w[1] = packtr(p1[4 * u + 2], p1[4 * u + 3]);
        *(int2v*)(prow + u * 8 + hi * 4) = w;
      }
      {
        short8_t pa2 = *(const short8_t*)(prow + hi * 8);
        short8_t pa3 = *(const short8_t*)(prow + 16 + hi * 8);
        __builtin_amdgcn_s_setprio(1);
#pragma unroll
        for (int db = 0; db < 4; ++db) {
          const unsigned short* vtd = VT + (db * 32 + q31) * 72;
          short8_t vf2 = *(const short8_t*)(vtd + 32 + hi * 8);
          short8_t vf3 = *(const short8_t*)(vtd + 48 + hi * 8);
          o[db] = mfma32(pa2, vf2, o[db]);
          o[db] = mfma32(pa3, vf3, o[db]);
        }
        __builtin_amdgcn_s_setprio(0);
      }
    }
    __syncthreads();
  }

  cl[q31] = l_run;
  f32x4 lv0 = *(const f32x4*)(cl + hi * 4);
  f32x4 lv1 = *(const f32x4*)(cl + 8 + hi * 4);
  f32x4 lv2 = *(const f32x4*)(cl + 16 + hi * 4);
  f32x4 lv3 = *(const f32x4*)(cl + 24 + hi * 4);
  f32x4 iv0, iv1, iv2, iv3;
#pragma unroll
  for (int r = 0; r < 4; ++r) {
    iv0[r] = 1.0f / lv0[r]; iv1[r] = 1.0f / lv1[r];
    iv2[r] = 1.0f / lv2[r]; iv3[r] = 1.0f / lv3[r];
  }
  unsigned short* ob = ao + ((size_t)(b * 2048 + a0) * 32 + h) * 128;
#pragma unroll
  for (int db = 0; db < 4; ++db) {
#pragma unroll
    for (int r = 0; r < 16; ++r) {
      int crow = (r & 3) + 8 * (r >> 2) + 4 * hi;
      float iv = (r < 4) ? iv0[r & 3] : (r < 8) ? iv1[r & 3] : (r < 12) ? iv2[r & 3] : iv3[r & 3];
      ob[(size_t)crow * 4096 + db * 32 + q31] = f2b(o[db][r] * iv);
    }
  }
}

// ---------------- launch ----------------
extern "C" void kernel_launch(void* const* d_in, const int* in_sizes, int n_in,
                              void* d_out, int out_size, void* d_ws, size_t ws_size,
                              hipStream_t stream) {
  const float* x  = (const float*)d_in[0];
  const float* wq = (const float*)d_in[1];
  const float* wk = (const float*)d_in[2];
  const float* wv = (const float*)d_in[3];
  const float* wo = (const float*)d_in[4];
  const float* fr = (const float*)d_in[7];
  float* out = (float*)d_out;

  char* ws = (char*)d_ws;
  unsigned short* xb  = (unsigned short*)(ws);               // 33.5MB; reused as ao
  unsigned short* wqb = (unsigned short*)(ws + 33554432);    // 33.5MB; reused as wob
  unsigned short* wkb = (unsigned short*)(ws + 67108864);    // 8.4MB
  unsigned short* wvb = (unsigned short*)(ws + 75497472);    // 8.4MB
  unsigned short* xq  = (unsigned short*)(ws + 83886080);    // 33.5MB
  unsigned short* xk  = (unsigned short*)(ws + 117440512);   // 8.4MB
  unsigned short* xvT = (unsigned short*)(ws + 125829120);   // 8.4MB (total 128MiB)
  unsigned short* ao  = xb;
  unsigned short* wob = wqb;

  dim3 blk(256);
  cvt_kernel<<<dim3(1024), blk, 0, stream>>>(x,  xb,  16777216 / 4);
  cvt_kernel<<<dim3(1024), blk, 0, stream>>>(wq, wqb, 16777216 / 4);
  cvt_kernel<<<dim3(512),  blk, 0, stream>>>(wk, wkb, 4194304 / 4);
  cvt_kernel<<<dim3(512),  blk, 0, stream>>>(wv, wvb, 4194304 / 4);

  gemm_q_kernel<<<dim3(16, 16), dim3(512), 0, stream>>>(xb, wqb, xq);
  gemm_kv_kernel<<<dim3(16, 32), dim3(256), 0, stream>>>(xb, wkb, wvb, xk, xvT);

  rope_kernel<32><<<dim3(2048), blk, 0, stream>>>(xq, fr, 2097152);
  rope_kernel<8><<<dim3(512),  blk, 0, stream>>>(xk, fr, 524288);

  cvt_kernel<<<dim3(1024), blk, 0, stream>>>(wo, wob, 16777216 / 4);

  attn_kernel<<<dim3(8, 32, 2), dim3(512), 0, stream>>>(xq, xk, xvT, ao);

  gemm_o_kernel<<<dim3(16, 16), dim3(512), 0, stream>>>(ao, wob, out);
}

// Round 18
// 506.045 us; speedup vs baseline: 1.3491x; 1.0496x over previous
//
#include <hip/hip_runtime.h>

typedef __bf16 bf16x8 __attribute__((ext_vector_type(8)));
typedef short short8_t __attribute__((ext_vector_type(8)));
typedef float f32x4 __attribute__((ext_vector_type(4)));
typedef float f32x16 __attribute__((ext_vector_type(16)));
typedef int int2v __attribute__((ext_vector_type(2)));
typedef unsigned short us4_t __attribute__((ext_vector_type(4)));

#define SCALE 0.08838834764831845f  // 1/sqrt(128)
#define CEXP 0.1275179f             // SCALE * log2(e)

#define VMCNT(n) asm volatile("s_waitcnt vmcnt(" #n ")" ::: "memory")

__device__ __forceinline__ float b2f(unsigned short u) {
  union { unsigned int i; float f; } v; v.i = ((unsigned int)u) << 16; return v.f;
}
__device__ __forceinline__ unsigned short f2b(float f) {
  union { float f; unsigned int i; } v; v.f = f;
  unsigned int r = v.i + 0x7fffu + ((v.i >> 16) & 1u);
  return (unsigned short)(r >> 16);
}
// truncating pack: low short = bf16(lo) (trunc), high short = bf16(hi) (trunc)
__device__ __forceinline__ int packtr(float lo, float hi_) {
  unsigned a = __builtin_bit_cast(unsigned, lo) >> 16;
  unsigned b = __builtin_bit_cast(unsigned, hi_) & 0xffff0000u;
  return (int)(a | b);
}

__device__ __forceinline__ f32x4 mfma16(short8_t a, short8_t b, f32x4 c) {
  return __builtin_amdgcn_mfma_f32_16x16x32_bf16(
      __builtin_bit_cast(bf16x8, a), __builtin_bit_cast(bf16x8, b), c, 0, 0, 0);
}
__device__ __forceinline__ f32x16 mfma32(short8_t a, short8_t b, f32x16 c) {
  return __builtin_amdgcn_mfma_f32_32x32x16_bf16(
      __builtin_bit_cast(bf16x8, a), __builtin_bit_cast(bf16x8, b), c, 0, 0, 0);
}

typedef __attribute__((address_space(1))) const void gas_t;
typedef __attribute__((address_space(3))) void las_t;
__device__ __forceinline__ void gload16(const void* g, void* l) {
  __builtin_amdgcn_global_load_lds((gas_t*)g, (las_t*)l, 16, 0, 0);
}

// ---------------- fp32 -> bf16 convert ----------------
__global__ void cvt_kernel(const float* __restrict__ src, unsigned short* __restrict__ dst, int n4) {
  for (int i = blockIdx.x * blockDim.x + threadIdx.x; i < n4; i += gridDim.x * blockDim.x) {
    f32x4 v = *(const f32x4*)(src + (size_t)i * 4);
    us4_t o;
    o[0] = f2b(v[0]); o[1] = f2b(v[1]); o[2] = f2b(v[2]); o[3] = f2b(v[3]);
    *(us4_t*)(dst + (size_t)i * 4) = o;
  }
}

// ============ 256x256 8-phase fine-interleaved GEMM core (T3+T4 port) ============
// BK=64, 2 LDS buffers x 64KB, 8 waves (2M x 4N), 4 phases per K64-tile:
//   P0: stage h0(t+1) | VMCNT(2) | barrier | read 8 frags | lgkm | 16 MFMA | barrier
//   P1: stage h1(t+1) + read 4   | barrier | lgkm | 16 MFMA | barrier
//   P2: stage h2(t+1) + read 8   | barrier | lgkm | 16 MFMA | barrier
//   P3: stage h3(t+1) + read 4   | barrier | lgkm | 16 MFMA | barrier
// Half-tiles: h0/h1 = A rows 0-127/128-255, h2/h3 = B rows 0-127/128-255 (16KB each).
// Swizzle: row r, 16B-block j stored at j ^ ((r>>1)&7) — both stage source and ds_read.
// VMCNT(2)@P0 confirms the 8 loads of the buffer about to be read (FIFO audit in notes).
// MODE: 0 = f32 out, 1 = bf16 out
template <int MODE>
__device__ __forceinline__ void gemm256_core(
    unsigned short* __restrict__ lds,
    const unsigned short* __restrict__ A, const unsigned short* __restrict__ Bt,
    void* __restrict__ Cout, int m0, int n0, int K, int ldc) {
  const int tid = threadIdx.x;
  const int wid = tid >> 6, lane = tid & 63;
  const int ln = lane & 15, lg = lane >> 4;
  const int wm = wid >> 2, wn = wid & 3;
  const int NT = K >> 6;   // K64 tiles (4096 -> 64)

  // ---- staging geometry: chunk c in [0,1024) per 16KB half-tile; thread covers c, c+512
  const int c0 = tid, c1 = tid + 512;
  const int r0 = c0 >> 3, r1 = c1 >> 3;                       // rows within half
  const int sb0 = (((c0 & 7) ^ ((r0 >> 1) & 7)) << 3);        // inverse-swizzled src k-off (elems)
  const int sb1 = (((c1 & 7) ^ ((r1 >> 1) & 7)) << 3);
  const unsigned short* gA0 = A + (size_t)(m0 + r0) * K + sb0;
  const unsigned short* gA1 = A + (size_t)(m0 + r1) * K + sb1;
  const unsigned short* gB0 = Bt + (size_t)(n0 + r0) * K + sb0;
  const unsigned short* gB1 = Bt + (size_t)(n0 + r1) * K + sb1;
  const size_t rowK128 = (size_t)128 * K;                     // +128 rows for halves 1/3
  unsigned short* d0 = lds + c0 * 8;                          // + buf*32768 + h*8192 (shorts)
  unsigned short* d1 = lds + c1 * 8;

  // ---- ds_read fragment addressing (bytes)
  const int s3 = (ln >> 1) & 7;
  const unsigned char* ldsb = (const unsigned char*)lds;
  const int abase = wm * 16384 + ln * 128;                          // + mi*2048 + jt + buf*65536
  const int bbase = 32768 + (wn >> 1) * 16384 + ((wn & 1) * 64 + ln) * 128;  // + nj*2048 + jt
  const int jt0 = ((lg) ^ s3) << 4;        // k-step 0
  const int jt1 = ((4 + lg) ^ s3) << 4;    // k-step 1

  f32x4 acc[8][4] = {};
  short8_t afL[4], afH[4], bf[4];

#define STG(h_, t_) { \
    const unsigned short* s0_; const unsigned short* s1_; \
    if ((h_) == 0) { s0_ = gA0; s1_ = gA1; } \
    else if ((h_) == 1) { s0_ = gA0 + rowK128; s1_ = gA1 + rowK128; } \
    else if ((h_) == 2) { s0_ = gB0; s1_ = gB1; } \
    else { s0_ = gB0 + rowK128; s1_ = gB1 + rowK128; } \
    unsigned short* dd = lds + ((t_) & 1) * 32768 + (h_) * 8192; \
    gload16(s0_ + (size_t)(t_) * 64, dd + (c0 - tid) * 0 + c0 * 8 - c0 * 8 + c0 * 8); \
    gload16(s1_ + (size_t)(t_) * 64, dd + c1 * 8); }

  // prologue: stage all 4 half-tiles of tile 0 into buffer 0
  STG(0, 0) STG(1, 0) STG(2, 0) STG(3, 0)

  for (int t = 0; t < NT; ++t) {
    const unsigned char* cb = ldsb + (t & 1) * 65536;
    // ---------- P0 ----------
    if (t + 1 < NT) { STG(0, t + 1) VMCNT(2); } else { VMCNT(0); }
    __builtin_amdgcn_s_barrier();
#pragma unroll
    for (int i = 0; i < 4; ++i)
      afL[i] = *(const short8_t*)(cb + abase + i * 2048 + jt0);
#pragma unroll
    for (int j = 0; j < 4; ++j)
      bf[j] = *(const short8_t*)(cb + bbase + j * 2048 + jt0);
    asm volatile("s_waitcnt lgkmcnt(0)" ::: "memory");
    __builtin_amdgcn_sched_barrier(0);
    __builtin_amdgcn_s_setprio(1);
#pragma unroll
    for (int i = 0; i < 4; ++i)
#pragma unroll
      for (int j = 0; j < 4; ++j)
        acc[i][j] = mfma16(afL[i], bf[j], acc[i][j]);
    __builtin_amdgcn_s_setprio(0);
    __builtin_amdgcn_s_barrier();
    // ---------- P1 ----------
    if (t + 1 < NT) STG(1, t + 1)
#pragma unroll
    for (int i = 0; i < 4; ++i)
      afH[i] = *(const short8_t*)(cb + abase + 8192 + i * 2048 + jt0);
    __builtin_amdgcn_s_barrier();
    asm volatile("s_waitcnt lgkmcnt(0)" ::: "memory");
    __builtin_amdgcn_sched_barrier(0);
    __builtin_amdgcn_s_setprio(1);
#pragma unroll
    for (int i = 0; i < 4; ++i)
#pragma unroll
      for (int j = 0; j < 4; ++j)
        acc[4 + i][j] = mfma16(afH[i], bf[j], acc[4 + i][j]);
    __builtin_amdgcn_s_setprio(0);
    __builtin_amdgcn_s_barrier();
    // ---------- P2 ----------
    if (t + 1 < NT) STG(2, t + 1)
#pragma unroll
    for (int i = 0; i < 4; ++i)
      afL[i] = *(const short8_t*)(cb + abase + i * 2048 + jt1);
#pragma unroll
    for (int j = 0; j < 4; ++j)
      bf[j] = *(const short8_t*)(cb + bbase + j * 2048 + jt1);
    __builtin_amdgcn_s_barrier();
    asm volatile("s_waitcnt lgkmcnt(0)" ::: "memory");
    __builtin_amdgcn_sched_barrier(0);
    __builtin_amdgcn_s_setprio(1);
#pragma unroll
    for (int i = 0; i < 4; ++i)
#pragma unroll
      for (int j = 0; j < 4; ++j)
        acc[i][j] = mfma16(afL[i], bf[j], acc[i][j]);
    __builtin_amdgcn_s_setprio(0);
    __builtin_amdgcn_s_barrier();
    // ---------- P3 ----------
    if (t + 1 < NT) STG(3, t + 1)
#pragma unroll
    for (int i = 0; i < 4; ++i)
      afH[i] = *(const short8_t*)(cb + abase + 8192 + i * 2048 + jt1);
    __builtin_amdgcn_s_barrier();
    asm volatile("s_waitcnt lgkmcnt(0)" ::: "memory");
    __builtin_amdgcn_sched_barrier(0);
    __builtin_amdgcn_s_setprio(1);
#pragma unroll
    for (int i = 0; i < 4; ++i)
#pragma unroll
      for (int j = 0; j < 4; ++j)
        acc[4 + i][j] = mfma16(afH[i], bf[j], acc[4 + i][j]);
    __builtin_amdgcn_s_setprio(0);
    __builtin_amdgcn_s_barrier();
  }
#undef STG

  // ---------- epilogue (same wave->C mapping as R12) ----------
#pragma unroll
  for (int mi = 0; mi < 8; ++mi) {
#pragma unroll
    for (int nj = 0; nj < 4; ++nj) {
#pragma unroll
      for (int r = 0; r < 4; ++r) {
        int row = m0 + wm * 128 + mi * 16 + lg * 4 + r;
        int col = n0 + wn * 64 + nj * 16 + ln;
        if (MODE == 1)
          ((unsigned short*)Cout)[(size_t)row * ldc + col] = f2b(acc[mi][nj][r]);
        else
          ((float*)Cout)[(size_t)row * ldc + col] = acc[mi][nj][r];
      }
    }
  }
}

// ============ 128x128 GEMM core (R6, verified) — for K/V projections ============
// MODE: 1 = bf16 out, 2 = bf16 transposed-V out
template <int MODE>
__device__ __forceinline__ void gemm128(unsigned short* __restrict__ ldsbuf,
                                        const unsigned short* __restrict__ A,
                                        const unsigned short* __restrict__ Bt,
                                        void* __restrict__ Cout,
                                        int m0, int n0, int K, int ldc) {
  unsigned short* As = ldsbuf;
  unsigned short* Bs = ldsbuf + 4096;
  const int tid = threadIdx.x;
  const int wave = tid >> 6, lane = tid & 63;
  const int ln = lane & 15, g = lane >> 4;
  const int wm = (wave >> 1) * 64, wn = (wave & 1) * 64;

  const int rA0 = wave * 16 + (lane >> 2);
  const int rA1 = 64 + wave * 16 + (lane >> 2);
  const int colx = (lane & 3) * 8;
  const unsigned short* gA0 = A + (size_t)(m0 + rA0) * K + colx;
  const unsigned short* gA1 = A + (size_t)(m0 + rA1) * K + colx;
  const unsigned short* gB0 = Bt + (size_t)(n0 + rA0) * K + colx;
  const unsigned short* gB1 = Bt + (size_t)(n0 + rA1) * K + colx;
  unsigned short* lA0 = As + wave * 512;
  unsigned short* lA1 = As + 2048 + wave * 512;
  unsigned short* lB0 = Bs + wave * 512;
  unsigned short* lB1 = Bs + 2048 + wave * 512;

  f32x4 acc[4][4] = {};

  for (int k0 = 0; k0 < K; k0 += 32) {
    gload16(gA0 + k0, lA0);
    gload16(gA1 + k0, lA1);
    gload16(gB0 + k0, lB0);
    gload16(gB1 + k0, lB1);
    __syncthreads();
    short8_t a[4], b[4];
#pragma unroll
    for (int i = 0; i < 4; ++i)
      a[i] = *(const short8_t*)(As + (wm + i * 16 + ln) * 32 + g * 8);
#pragma unroll
    for (int j = 0; j < 4; ++j)
      b[j] = *(const short8_t*)(Bs + (wn + j * 16 + ln) * 32 + g * 8);
#pragma unroll
    for (int i = 0; i < 4; ++i)
#pragma unroll
      for (int j = 0; j < 4; ++j)
        acc[i][j] = mfma16(a[i], b[j], acc[i][j]);
    __syncthreads();
  }

#pragma unroll
  for (int i = 0; i < 4; ++i) {
#pragma unroll
    for (int j = 0; j < 4; ++j) {
      if (MODE == 2) {
        int row0 = m0 + wm + i * 16 + g * 4;
        int col = n0 + wn + j * 16 + ln;
        us4_t pk;
#pragma unroll
        for (int r = 0; r < 4; ++r) pk[r] = f2b(acc[i][j][r]);
        *(us4_t*)((unsigned short*)Cout +
                  ((size_t)((row0 >> 11) * 1024 + col)) * 2048 + (row0 & 2047)) = pk;
      } else {
#pragma unroll
        for (int r = 0; r < 4; ++r) {
          int row = m0 + wm + i * 16 + g * 4 + r;
          int col = n0 + wn + j * 16 + ln;
          ((unsigned short*)Cout)[(size_t)row * ldc + col] = f2b(acc[i][j][r]);
        }
      }
    }
  }
}

// Q projection: grid (16,16), 256 tiles exactly = 1 full round of 256 CUs.
__global__ __launch_bounds__(512, 1) void gemm_q_kernel(
    const unsigned short* __restrict__ xb, const unsigned short* __restrict__ wqb,
    unsigned short* __restrict__ xq) {
  __shared__ __align__(16) unsigned short lds[65536];
  gemm256_core<1>(lds, xb, wqb, xq, blockIdx.y * 256, blockIdx.x * 256, 4096, 4096);
}

// K/V projections: grid (16, 32), 128^2 tiles, high occupancy (16 KB LDS).
__global__ __launch_bounds__(256) void gemm_kv_kernel(
    const unsigned short* __restrict__ xb, const unsigned short* __restrict__ wkb,
    const unsigned short* __restrict__ wvb, unsigned short* __restrict__ xk,
    unsigned short* __restrict__ xvT) {
  __shared__ __align__(16) unsigned short lds[8192];
  int bx = blockIdx.x, by = blockIdx.y;
  if (bx < 8) gemm128<1>(lds, xb, wkb, xk, by * 128, bx * 128, 4096, 1024);
  else        gemm128<2>(lds, xb, wvb, xvT, by * 128, (bx - 8) * 128, 4096, 0);
}

__global__ __launch_bounds__(512, 1) void gemm_o_kernel(
    const unsigned short* __restrict__ ao, const unsigned short* __restrict__ wob,
    float* __restrict__ out) {
  __shared__ __align__(16) unsigned short lds[65536];
  gemm256_core<0>(lds, ao, wob, out, blockIdx.y * 256, blockIdx.x * 256, 4096, 4096);
}

// ---------------- RoPE ----------------
template <int NH>
__global__ void rope_kernel(unsigned short* __restrict__ p, const float* __restrict__ fr,
                            int nchunks) {
  for (int c = blockIdx.x * blockDim.x + threadIdx.x; c < nchunks;
       c += gridDim.x * blockDim.x) {
    size_t e = (size_t)c * 8;
    int f0 = (c & 15) * 4;
    int rest = (int)(e >> 7);
    int s = (rest / NH) & 2047;
    unsigned short* ptr = p + e;
    short8_t v = *(short8_t*)ptr;
    const float* cosp = fr + (size_t)s * 64 + f0;
    const float* sinp = cosp + 131072;
#pragma unroll
    for (int j = 0; j < 4; ++j) {
      float re = b2f((unsigned short)v[2 * j]);
      float im = b2f((unsigned short)v[2 * j + 1]);
      float cc = cosp[j], ss = sinp[j];
      v[2 * j]     = (short)f2b(re * cc - im * ss);
      v[2 * j + 1] = (short)f2b(re * ss + im * cc);
    }
    *(short8_t*)ptr = v;
  }
}

// ---------------- flash attention (R17 verified): 8 waves x 32 q-rows, 32x32 MFMA ----------------
__global__ __launch_bounds__(512, 2) void attn_kernel(
    const unsigned short* __restrict__ xq, const unsigned short* __restrict__ xk,
    const unsigned short* __restrict__ xvT, unsigned short* __restrict__ ao) {
  __shared__ __align__(16) unsigned char smem[56320];
  const int tid = threadIdx.x;
  const int wq = tid >> 6, lane = tid & 63;
  const int q31 = lane & 31, hi = lane >> 5;
  const int bx = blockIdx.z ? (int)blockIdx.x : 7 - (int)blockIdx.x;
  const int h = blockIdx.y, b = blockIdx.z;
  const int hkv = h >> 2;
  const int q0 = bx * 256;
  const int a0 = q0 + wq * 32;
  const int ktmax_w = a0 >> 6;
  const int NT = bx * 4 + 4;

  const unsigned short* kbase = xk + ((size_t)(b * 2048) * 8 + hkv) * 128;
  const unsigned short* vtg = xvT + (size_t)(b * 1024 + hkv * 128) * 2048;

  const unsigned short* qrow = xq + ((size_t)(b * 2048 + a0 + q31) * 32 + h) * 128;
  short8_t qf[8];
#pragma unroll
  for (int st = 0; st < 8; ++st) qf[st] = *(const short8_t*)(qrow + st * 16 + hi * 8);

  const int c0 = tid, c1 = tid + 512;
  const int kg0 = (c0 >> 4) * 1024 + (c0 & 15) * 8;
  const int kg1 = (c1 >> 4) * 1024 + (c1 & 15) * 8;
  const int ka0 = (c0 >> 4) * 256 + (((c0 & 15) ^ ((c0 >> 4) & 7)) << 4);
  const int ka1 = (c1 >> 4) * 256 + (((c1 & 15) ^ ((c1 >> 4) & 7)) << 4);
  const int d0 = tid >> 3, kb0 = tid & 7, d1v = d0 + 64;
  const int vg0 = d0 * 2048 + kb0 * 8, vg1 = d1v * 2048 + kb0 * 8;
  const int va0 = d0 * 72 + kb0 * 8, va1 = d1v * 72 + kb0 * 8;

  unsigned short* Kb = (unsigned short*)(smem);
  unsigned short* VT = (unsigned short*)(smem + 16384);
  unsigned short* pp = (unsigned short*)(smem + 34816) + wq * 1280;
  unsigned short* prow = pp + q31 * 40;
  float* cl = (float*)(smem + 55296) + wq * 32;

  f32x16 o[4] = {};
  float m_run = -1e30f, l_run = 0.f;

  short8_t kr0 = *(const short8_t*)(kbase + kg0);
  short8_t kr1 = *(const short8_t*)(kbase + kg1);
  short8_t vr0 = *(const short8_t*)(vtg + vg0);
  short8_t vr1 = *(const short8_t*)(vtg + vg1);

  for (int kt = 0; kt < NT; ++kt) {
    *(short8_t*)((unsigned char*)Kb + ka0) = kr0;
    *(short8_t*)((unsigned char*)Kb + ka1) = kr1;
    *(short8_t*)(VT + va0) = vr0;
    *(short8_t*)(VT + va1) = vr1;
    __syncthreads();
    if (kt + 1 < NT) {
      const unsigned short* kg = kbase + (size_t)(kt + 1) * 65536;
      kr0 = *(const short8_t*)(kg + kg0);
      kr1 = *(const short8_t*)(kg + kg1);
      vr0 = *(const short8_t*)(vtg + vg0 + (kt + 1) * 64);
      vr1 = *(const short8_t*)(vtg + vg1 + (kt + 1) * 64);
    }

    if (kt <= ktmax_w) {
      const int r7 = (q31 & 7) << 4;
      f32x16 p0 = {}, p1 = {};
      __builtin_amdgcn_s_setprio(1);
#pragma unroll
      for (int st = 0; st < 8; ++st) {
        int cb = (((st * 2 + hi) << 4)) ^ r7;
        short8_t k0 = *(const short8_t*)((const unsigned char*)Kb + q31 * 256 + cb);
        short8_t k1 = *(const short8_t*)((const unsigned char*)Kb + (q31 + 32) * 256 + cb);
        p0 = mfma32(k0, qf[st], p0);
        p1 = mfma32(k1, qf[st], p1);
      }
      __builtin_amdgcn_s_setprio(0);

      if (kt == ktmax_w) {
        const int q = a0 + q31;
#pragma unroll
        for (int r = 0; r < 16; ++r) {
          int crow = (r & 3) + 8 * (r >> 2) + 4 * hi;
          int kgl = kt * 64 + crow;
          if (kgl > q) p0[r] = -1e30f;
          if (kgl + 32 > q) p1[r] = -1e30f;
        }
      }
      // ---- online softmax with defer-max (T13) ----
      float mx = -1e30f;
#pragma unroll
      for (int r = 0; r < 16; ++r) mx = fmaxf(mx, fmaxf(p0[r], p1[r]));
      mx = fmaxf(mx, __shfl_xor(mx, 32));
      const bool defer = __all(mx <= m_run + 30.0f);
      const float mnew = defer ? m_run : fmaxf(m_run, mx);
      float sum = 0.f;
#pragma unroll
      for (int r = 0; r < 16; ++r) {
        p0[r] = exp2f((p0[r] - mnew) * CEXP);
        p1[r] = exp2f((p1[r] - mnew) * CEXP);
        sum += p0[r] + p1[r];
      }
      sum += __shfl_xor(sum, 32);
      if (defer) {
        l_run += sum;
      } else {
        float corr = exp2f((m_run - mnew) * CEXP);
        m_run = mnew;
        l_run = l_run * corr + sum;
        cl[q31] = corr;
        f32x4 cv0 = *(const f32x4*)(cl + hi * 4);
        f32x4 cv1 = *(const f32x4*)(cl + 8 + hi * 4);
        f32x4 cv2 = *(const f32x4*)(cl + 16 + hi * 4);
        f32x4 cv3 = *(const f32x4*)(cl + 24 + hi * 4);
#pragma unroll
        for (int db = 0; db < 4; ++db) {
#pragma unroll
          for (int r = 0; r < 4; ++r) {
            o[db][r]      *= cv0[r];
            o[db][4 + r]  *= cv1[r];
            o[db][8 + r]  *= cv2[r];
            o[db][12 + r] *= cv3[r];
          }
        }
      }

#pragma unroll
      for (int u = 0; u < 4; ++u) {
        int2v w;
        w[0] = packtr(p0[4 * u], p0[4 * u + 1]);
        w[1] = packtr(p0[4 * u + 2], p0[4 * u + 3]);
        *(int2v*)(prow + u * 8 + hi * 4) = w;
      }
      {
        short8_t pa0 = *(const short8_t*)(prow + hi * 8);
        short8_t pa1 = *(const short8_t*)(prow + 16 + hi * 8);
        __builtin_amdgcn_s_setprio(1);
#pragma unroll
        for (int db = 0; db < 4; ++db) {
          const unsigned short* vtd = VT + (db * 32 + q31) * 72;
          short8_t vf0 = *(const short8_t*)(vtd + hi * 8);
          short8_t vf1 = *(const short8_t*)(vtd + 16 + hi * 8);
          o[db] = mfma32(pa0, vf0, o[db]);
          o[db] = mfma32(pa1, vf1, o[db]);
        }
        __builtin_amdgcn_s_setprio(0);
      }
#pragma unroll
      for (int u = 0; u < 4; ++u) {
        int2v w;
        w[0] = packtr(p1[4 * u], p1[4 * u + 1]);
        w[1] = packtr(p1[4 * u + 2], p1[4 * u + 3]);
        *(int2v*)(prow + u * 8 + hi * 4) = w;
      }
      {
        short8_t pa2 = *(const short8_t*)(prow + hi * 8);
        short8_t pa3 = *(const short8_t*)(prow + 16 + hi * 8);
        __builtin_amdgcn_s_setprio(1);
#pragma unroll
        for (int db = 0; db < 4; ++db) {
          const unsigned short* vtd = VT + (db * 32 + q31) * 72;
          short8_t vf2 = *(const short8_t*)(vtd + 32 + hi * 8);
          short8_t vf3 = *(const short8_t*)(vtd + 48 + hi * 8);
          o[db] = mfma32(pa2, vf2, o[db]);
          o[db] = mfma32(pa3, vf3, o[db]);
        }
        __builtin_amdgcn_s_setprio(0);
      }
    }
    __syncthreads();
  }

  cl[q31] = l_run;
  f32x4 lv0 = *(const f32x4*)(cl + hi * 4);
  f32x4 lv1 = *(const f32x4*)(cl + 8 + hi * 4);
  f32x4 lv2 = *(const f32x4*)(cl + 16 + hi * 4);
  f32x4 lv3 = *(const f32x4*)(cl + 24 + hi * 4);
  f32x4 iv0, iv1, iv2, iv3;
#pragma unroll
  for (int r = 0; r < 4; ++r) {
    iv0[r] = 1.0f / lv0[r]; iv1[r] = 1.0f / lv1[r];
    iv2[r] = 1.0f / lv2[r]; iv3[r] = 1.0f / lv3[r];
  }
  unsigned short* ob = ao + ((size_t)(b * 2048 + a0) * 32 + h) * 128;
#pragma unroll
  for (int db = 0; db < 4; ++db) {
#pragma unroll
    for (int r = 0; r < 16; ++r) {
      int crow = (r & 3) + 8 * (r >> 2) + 4 * hi;
      float iv = (r < 4) ? iv0[r & 3] : (r < 8) ? iv1[r & 3] : (r < 12) ? iv2[r & 3] : iv3[r & 3];
      ob[(size_t)crow * 4096 + db * 32 + q31] = f2b(o[db][r] * iv);
    }
  }
}

// ---------------- launch ----------------
extern "C" void kernel_launch(void* const* d_in, const int* in_sizes, int n_in,
                              void* d_out, int out_size, void* d_ws, size_t ws_size,
                              hipStream_t stream) {
  const float* x  = (const float*)d_in[0];
  const float* wq = (const float*)d_in[1];
  const float* wk = (const float*)d_in[2];
  const float* wv = (const float*)d_in[3];
  const float* wo = (const float*)d_in[4];
  const float* fr = (const float*)d_in[7];
  float* out = (float*)d_out;

  char* ws = (char*)d_ws;
  unsigned short* xb  = (unsigned short*)(ws);               // 33.5MB; reused as ao
  unsigned short* wqb = (unsigned short*)(ws + 33554432);    // 33.5MB; reused as wob
  unsigned short* wkb = (unsigned short*)(ws + 67108864);    // 8.4MB
  unsigned short* wvb = (unsigned short*)(ws + 75497472);    // 8.4MB
  unsigned short* xq  = (unsigned short*)(ws + 83886080);    // 33.5MB
  unsigned short* xk  = (unsigned short*)(ws + 117440512);   // 8.4MB
  unsigned short* xvT = (unsigned short*)(ws + 125829120);   // 8.4MB (total 128MiB)
  unsigned short* ao  = xb;
  unsigned short* wob = wqb;

  dim3 blk(256);
  cvt_kernel<<<dim3(1024), blk, 0, stream>>>(x,  xb,  16777216 / 4);
  cvt_kernel<<<dim3(1024), blk, 0, stream>>>(wq, wqb, 16777216 / 4);
  cvt_kernel<<<dim3(512),  blk, 0, stream>>>(wk, wkb, 4194304 / 4);
  cvt_kernel<<<dim3(512),  blk, 0, stream>>>(wv, wvb, 4194304 / 4);

  gemm_q_kernel<<<dim3(16, 16), dim3(512), 0, stream>>>(xb, wqb, xq);
  gemm_kv_kernel<<<dim3(16, 32), dim3(256), 0, stream>>>(xb, wkb, wvb, xk, xvT);

  rope_kernel<32><<<dim3(2048), blk, 0, stream>>>(xq, fr, 2097152);
  rope_kernel<8><<<dim3(512),  blk, 0, stream>>>(xk, fr, 524288);

  cvt_kernel<<<dim3(1024), blk, 0, stream>>>(wo, wob, 16777216 / 4);

  attn_kernel<<<dim3(8, 32, 2), dim3(512), 0, stream>>>(xq, xk, xvT, ao);

  gemm_o_kernel<<<dim3(16, 16), dim3(512), 0, stream>>>(ao, wob, out);
}